// Round 2
// baseline (382.332 us; speedup 1.0000x reference)
//
#include <hip/hip_runtime.h>
#include <hip/hip_fp16.h>
#include <math.h>

// ---------------------------------------------------------------------------
// GCN (3-layer feature + 3-layer attention) + segment softmax + attention
// pooling + MLP.
// R8: fill_kernel (43us, 53MB WRITE vs 6.4MB payload = 8.3x line-writeback
//     amplification from cross-XCD random scatter) replaced by a two-pass
//     bucketed counting sort:
//       ebucket: LDS-histogram binning -> contiguous frontier appends
//       esort:   per-bucket scatter, grid-swizzled so each bucket's region
//                is touched by exactly one XCD's L2 (bid = s*16 + b).
// ---------------------------------------------------------------------------

#define DIN 128
#define FH  128
#define DOUT 256
#define NBUK 16

typedef float f4 __attribute__((ext_vector_type(4)));
typedef float f32x4 __attribute__((ext_vector_type(4)));
typedef _Float16 h8v __attribute__((ext_vector_type(8)));
typedef _Float16 h4v __attribute__((ext_vector_type(4)));

// ---------------- graph prep ----------------

__global__ void hist_kernel(const int* __restrict__ dst, int* __restrict__ cnt, int E) {
    int e = blockIdx.x * 256 + threadIdx.x;
    if (e < E) atomicAdd(&cnt[dst[e]], 1);
}

__global__ void dinv_kernel(const int* __restrict__ cnt, float* __restrict__ dinv, int n) {
    int i = blockIdx.x * 256 + threadIdx.x;
    if (i < n) dinv[i] = rsqrtf((float)(cnt[i] + 1));   // +1 self loop
}

__global__ __launch_bounds__(256) void scan1_kernel(const int* __restrict__ cnt,
                                                    int* __restrict__ bsum, int n) {
    __shared__ int sm[256];
    int tid = threadIdx.x;
    int base = blockIdx.x * 512;
    int a = (base + tid < n) ? cnt[base + tid] : 0;
    int b = (base + 256 + tid < n) ? cnt[base + 256 + tid] : 0;
    sm[tid] = a + b;
    __syncthreads();
    for (int off = 128; off > 0; off >>= 1) {
        if (tid < off) sm[tid] += sm[tid + off];
        __syncthreads();
    }
    if (tid == 0) bsum[blockIdx.x] = sm[0];
}

__global__ void scan2_kernel(const int* __restrict__ bsum, int* __restrict__ boff,
                             int* __restrict__ rpN, int nb) {
    if (threadIdx.x == 0) {
        int run = 0;
        for (int i = 0; i < nb; ++i) { boff[i] = run; run += bsum[i]; }
        *rpN = run;
    }
}

__global__ __launch_bounds__(256) void scan3_kernel(const int* __restrict__ cnt,
        const int* __restrict__ boff, int* __restrict__ rp, int n) {
    __shared__ int sm[256];
    int tid = threadIdx.x;
    int base = blockIdx.x * 512;
    int i0 = base + 2 * tid;
    int c0 = (i0 < n) ? cnt[i0] : 0;
    int c1 = (i0 + 1 < n) ? cnt[i0 + 1] : 0;
    int ps = c0 + c1;
    sm[tid] = ps;
    __syncthreads();
    for (int off = 1; off < 256; off <<= 1) {
        int v = (tid >= off) ? sm[tid - off] : 0;
        __syncthreads();
        sm[tid] += v;
        __syncthreads();
    }
    int excl = sm[tid] - ps + boff[blockIdx.x];
    if (i0 < n) rp[i0] = excl;
    if (i0 + 1 < n) rp[i0 + 1] = excl + c0;
}

// Pass A: bin edges into NBUK dst-range buckets. Per-block LDS histogram ->
// one global atomic per (block,bucket) -> contiguous frontier appends.
__global__ __launch_bounds__(256) void ebucket_kernel(const int* __restrict__ src,
        const int* __restrict__ dst, int* __restrict__ bcur,
        unsigned long long* __restrict__ entries, int E, int shift) {
    __shared__ int lcnt[NBUK], lbase[NBUK], lcur[NBUK];
    const int tid = threadIdx.x;
    const int e0 = blockIdx.x * 2048;
    if (tid < NBUK) lcnt[tid] = 0;
    __syncthreads();
    int s_[8], d_[8];
    #pragma unroll
    for (int k = 0; k < 8; ++k) {
        int e = e0 + k * 256 + tid;
        if (e < E) {
            s_[k] = src[e];
            d_[k] = dst[e];
            atomicAdd(&lcnt[d_[k] >> shift], 1);
        } else {
            d_[k] = -1;
        }
    }
    __syncthreads();
    if (tid < NBUK) {
        lbase[tid] = lcnt[tid] ? atomicAdd(&bcur[tid], lcnt[tid]) : 0;
        lcur[tid] = 0;
    }
    __syncthreads();
    #pragma unroll
    for (int k = 0; k < 8; ++k) {
        if (d_[k] >= 0) {
            int b = d_[k] >> shift;
            int idx = atomicAdd(&lcur[b], 1);
            entries[(size_t)(lbase[b] + idx)] =
                ((unsigned long long)(unsigned)d_[k] << 32) | (unsigned)s_[k];
        }
    }
}

// Pass B: final-position scatter within one bucket's region. Grid is
// bid = s*NBUK + b so bucket b runs entirely on XCD b%8 (round-robin
// dispatch) -> its ~500KB cn region stays in one L2, dirty lines written
// back once.
__global__ __launch_bounds__(256) void esort_kernel(
        const unsigned long long* __restrict__ entries,
        const int* __restrict__ rp, int* __restrict__ fillc,
        const float* __restrict__ dinv, long long* __restrict__ cn,
        int n, int shift) {
    constexpr int SPB = 64;
    const int b = blockIdx.x & (NBUK - 1);
    const int s = blockIdx.x >> 4;
    const int n0 = min(b << shift, n);
    const int n1 = min((b + 1) << shift, n);
    const int lo = rp[n0], hi = rp[n1];
    const int len = hi - lo;
    if (len <= 0) return;
    const int chunk = (len + SPB - 1) / SPB;
    const int a0 = lo + s * chunk;
    const int a1 = min(a0 + chunk, hi);
    for (int i = a0 + threadIdx.x; i < a1; i += 256) {
        unsigned long long v = entries[i];
        int sx = (int)(unsigned)(v & 0xffffffffu);
        int d  = (int)(unsigned)(v >> 32);
        int p = rp[d] + atomicAdd(&fillc[d], 1);
        float w = dinv[sx] * dinv[d];
        cn[p] = (long long)(unsigned)sx | ((long long)__float_as_int(w) << 32);
    }
}

// gstart (binary search per graph) + bucket cursor init (needs rp).
__global__ void gstart_kernel(const int* __restrict__ batch, int* __restrict__ gstart,
                              const int* __restrict__ rp, int* __restrict__ bcur,
                              int n, int g, int shift) {
    int t = threadIdx.x;
    if (t < NBUK) bcur[t] = rp[min(t << shift, n)];
    if (t > g) return;
    int lo = 0, hi = n;
    while (lo < hi) {
        int mid = (lo + hi) >> 1;
        if (batch[mid] < t) lo = mid + 1; else hi = mid;
    }
    gstart[t] = lo;
}

// fp32 -> fp16 convert (8 elems / thread)
__global__ void cvt16_kernel(const float* __restrict__ in, __half* __restrict__ outh,
                             long n8) {
    long i = (long)blockIdx.x * 256 + threadIdx.x;
    if (i >= n8) return;
    f4 a = ((const f4*)in)[2 * i];
    f4 b = ((const f4*)in)[2 * i + 1];
    __half2 h0 = __float22half2_rn(make_float2(a.x, a.y));
    __half2 h1 = __float22half2_rn(make_float2(a.z, a.w));
    __half2 h2 = __float22half2_rn(make_float2(b.x, b.y));
    __half2 h3 = __float22half2_rn(make_float2(b.z, b.w));
    uint4 st;
    st.x = *(unsigned*)&h0; st.y = *(unsigned*)&h1;
    st.z = *(unsigned*)&h2; st.w = *(unsigned*)&h3;
    ((uint4*)outh)[i] = st;
}

// ---------------- weight prep: split-fp16 transpose ----------------

__device__ __forceinline__ void wsplit(const float* __restrict__ W,
        _Float16* __restrict__ Th, _Float16* __restrict__ Tl,
        int fin, int fout, int i) {
    int r = i / fout, c = i % fout;
    float w = W[i];
    _Float16 h = (_Float16)w;
    Th[c * fin + r] = h;
    Tl[c * fin + r] = (_Float16)(w - (float)h);
}

// WT half-offsets: W1h=0 W1l=16384 W2h=32768 W2l=49152 W3h=65536 W3l=81920
//                  A1h=98304 A1l=106496 A2h=114688 A2l=116736  (total 118784)
__global__ __launch_bounds__(256) void wprep_kernel(const float* __restrict__ W1,
        const float* __restrict__ W2, const float* __restrict__ W3,
        const float* __restrict__ A1, const float* __restrict__ A2,
        _Float16* __restrict__ T) {
    int i = blockIdx.x * 256 + threadIdx.x;
    if (i < 16384)       wsplit(W1, T,          T + 16384,  128, 128, i);
    else if (i < 32768)  wsplit(W2, T + 32768,  T + 49152,  128, 128, i - 16384);
    else if (i < 49152)  wsplit(W3, T + 65536,  T + 81920,  128, 128, i - 32768);
    else if (i < 57344)  wsplit(A1, T + 98304,  T + 106496, 128, 64,  i - 49152);
    else if (i < 59392)  wsplit(A2, T + 114688, T + 116736, 64,  32,  i - 57344);
}

// ---------------- MFMA dense linear: C = A[n,FIN] @ W[FIN,FOUT] ----------
// Split-fp16: acc = Ah*Wh + Ah*Wl + Al*Wh (fp32 MFMA accumulate).
// OMODE: 1 = fp32 out + bias + relu, 2 = fp16 out (no bias).

template<int FIN, int FOUT, int OMODE>
__global__ __launch_bounds__(256) void mgemm_kernel(const float* __restrict__ A,
        const _Float16* __restrict__ Wh, const _Float16* __restrict__ Wl,
        const float* __restrict__ bias, void* __restrict__ Cv, int n) {
    constexpr int NWC  = (FOUT / 16 < 4) ? FOUT / 16 : 4;  // waves across cols
    constexpr int NWR  = 4 / NWC;                          // waves across rows
    constexpr int BM   = 64 * NWR;                         // rows per block
    constexpr int CT   = FOUT / 16 / NWC;                  // col tiles per wave
    constexpr int KS   = FIN / 32;                         // K steps
    constexpr int LSTR = FIN + 8;                          // LDS row stride (halfs)
    __shared__ _Float16 Ahs[BM * LSTR];
    __shared__ _Float16 Als[BM * LSTR];

    const int tid  = threadIdx.x;
    const int w    = tid >> 6;
    const int lane = tid & 63;
    const long row0 = (long)blockIdx.x * BM;

    // stage A tile -> LDS, split fp32 -> fp16 high/low
    for (int i = tid; i < BM * (FIN / 4); i += 256) {
        int r  = i / (FIN / 4);
        int c4 = i % (FIN / 4);
        long gr = row0 + r;
        float4 v = {0.f, 0.f, 0.f, 0.f};
        if (gr < n) v = *(const float4*)&A[gr * FIN + c4 * 4];
        _Float16 h0 = (_Float16)v.x, h1 = (_Float16)v.y;
        _Float16 h2 = (_Float16)v.z, h3 = (_Float16)v.w;
        h4v hh = {h0, h1, h2, h3};
        h4v ll = {(_Float16)(v.x - (float)h0), (_Float16)(v.y - (float)h1),
                  (_Float16)(v.z - (float)h2), (_Float16)(v.w - (float)h3)};
        *(h4v*)&Ahs[r * LSTR + c4 * 4] = hh;
        *(h4v*)&Als[r * LSTR + c4 * 4] = ll;
    }

    // B fragments (registers, L2-resident weight reads)
    const int wc = w % NWC;
    const int wr = w / NWC;
    const int colbase = wc * CT * 16;
    const int bk = (lane >> 4) * 8;
    h8v Bh[CT][KS], Bl[CT][KS];
    #pragma unroll
    for (int ct = 0; ct < CT; ++ct) {
        int c = colbase + ct * 16 + (lane & 15);
        #pragma unroll
        for (int kk = 0; kk < KS; ++kk) {
            Bh[ct][kk] = *(const h8v*)&Wh[(size_t)c * FIN + kk * 32 + bk];
            Bl[ct][kk] = *(const h8v*)&Wl[(size_t)c * FIN + kk * 32 + bk];
        }
    }

    __syncthreads();

    f32x4 acc[4][CT];
    #pragma unroll
    for (int rt = 0; rt < 4; ++rt)
        #pragma unroll
        for (int ct = 0; ct < CT; ++ct)
            acc[rt][ct] = (f32x4){0.f, 0.f, 0.f, 0.f};

    #pragma unroll
    for (int rt = 0; rt < 4; ++rt) {
        const int r = wr * 64 + rt * 16 + (lane & 15);
        #pragma unroll
        for (int kk = 0; kk < KS; ++kk) {
            h8v ah = *(const h8v*)&Ahs[r * LSTR + kk * 32 + bk];
            h8v al = *(const h8v*)&Als[r * LSTR + kk * 32 + bk];
            #pragma unroll
            for (int ct = 0; ct < CT; ++ct) {
                acc[rt][ct] = __builtin_amdgcn_mfma_f32_16x16x32_f16(
                    ah, Bh[ct][kk], acc[rt][ct], 0, 0, 0);
                acc[rt][ct] = __builtin_amdgcn_mfma_f32_16x16x32_f16(
                    ah, Bl[ct][kk], acc[rt][ct], 0, 0, 0);
                acc[rt][ct] = __builtin_amdgcn_mfma_f32_16x16x32_f16(
                    al, Bh[ct][kk], acc[rt][ct], 0, 0, 0);
            }
        }
    }

    // epilogue: C/D layout col = lane&15, row = (lane>>4)*4 + j  [verified]
    #pragma unroll
    for (int rt = 0; rt < 4; ++rt) {
        const long rbase = row0 + wr * 64 + rt * 16 + (lane >> 4) * 4;
        #pragma unroll
        for (int ct = 0; ct < CT; ++ct) {
            const int col = colbase + ct * 16 + (lane & 15);
            if (OMODE == 1) {
                const float bv = bias[col];
                #pragma unroll
                for (int j = 0; j < 4; ++j) {
                    long r = rbase + j;
                    if (r < n)
                        ((float*)Cv)[r * FOUT + col] = fmaxf(acc[rt][ct][j] + bv, 0.f);
                }
            } else {
                #pragma unroll
                for (int j = 0; j < 4; ++j) {
                    long r = rbase + j;
                    if (r < n)
                        ((__half*)Cv)[r * FOUT + col] = __float2half(acc[rt][ct][j]);
                }
            }
        }
    }
}

// final attention linear: [n,32] @ [32,1]
__global__ void a3_kernel(const float* __restrict__ A, const float* __restrict__ W,
                          float* __restrict__ out, int n) {
    int i = blockIdx.x * 256 + threadIdx.x;
    if (i >= n) return;
    const float4* a = (const float4*)(A + (size_t)i * 32);
    float acc = 0.f;
    #pragma unroll
    for (int q = 0; q < 8; ++q) {
        float4 v = a[q];
        float4 w = ((const float4*)W)[q];
        acc += v.x * w.x + v.y * w.y + v.z * w.z + v.w * w.w;
    }
    out[i] = acc;
}

// ---------------- fp16-gather aggregation ----------------

__device__ __forceinline__ void hacc8(float acc[8], uint4 u, float w) {
    __half2 h; float2 f;
    h = *(__half2*)&u.x; f = __half22float2(h); acc[0] += w * f.x; acc[1] += w * f.y;
    h = *(__half2*)&u.y; f = __half22float2(h); acc[2] += w * f.x; acc[3] += w * f.y;
    h = *(__half2*)&u.z; f = __half22float2(h); acc[4] += w * f.x; acc[5] += w * f.y;
    h = *(__half2*)&u.w; f = __half22float2(h); acc[6] += w * f.x; acc[7] += w * f.y;
}

template<int F, bool BR>
__global__ __launch_bounds__(256) void aggh_kernel(const __half* __restrict__ tin,
        const float* __restrict__ bias, const float* __restrict__ dinv,
        const int* __restrict__ rp, const long long* __restrict__ cn,
        float* __restrict__ out, int n) {
    constexpr int LPR   = F / 8;
    constexpr int SLOTS = 64 / LPR;
    const int lane = threadIdx.x & 63;
    const int node = blockIdx.x * 4 + (threadIdx.x >> 6);
    if (node >= n) return;
    const int l    = lane % LPR;
    const int slot = lane / LPR;
    const uint4* base = (const uint4*)tin + l;
    const int e0 = rp[node], e1 = rp[node + 1];
    float acc[8] = {0.f, 0.f, 0.f, 0.f, 0.f, 0.f, 0.f, 0.f};
    if (slot == 0) {
        float di = dinv[node];
        uint4 u = base[(size_t)node * LPR];
        hacc8(acc, u, di * di);
    }
    int p = e0 + slot;
    for (; p + 3 * SLOTS < e1; p += 4 * SLOTS) {
        long long r0 = __builtin_nontemporal_load(cn + p);
        long long r1 = __builtin_nontemporal_load(cn + p + SLOTS);
        long long r2 = __builtin_nontemporal_load(cn + p + 2 * SLOTS);
        long long r3 = __builtin_nontemporal_load(cn + p + 3 * SLOTS);
        uint4 u0 = base[(size_t)(unsigned)r0 * LPR];
        uint4 u1 = base[(size_t)(unsigned)r1 * LPR];
        uint4 u2 = base[(size_t)(unsigned)r2 * LPR];
        uint4 u3 = base[(size_t)(unsigned)r3 * LPR];
        hacc8(acc, u0, __int_as_float((int)(r0 >> 32)));
        hacc8(acc, u1, __int_as_float((int)(r1 >> 32)));
        hacc8(acc, u2, __int_as_float((int)(r2 >> 32)));
        hacc8(acc, u3, __int_as_float((int)(r3 >> 32)));
    }
    for (; p + SLOTS < e1; p += 2 * SLOTS) {
        long long r0 = __builtin_nontemporal_load(cn + p);
        long long r1 = __builtin_nontemporal_load(cn + p + SLOTS);
        uint4 u0 = base[(size_t)(unsigned)r0 * LPR];
        uint4 u1 = base[(size_t)(unsigned)r1 * LPR];
        hacc8(acc, u0, __int_as_float((int)(r0 >> 32)));
        hacc8(acc, u1, __int_as_float((int)(r1 >> 32)));
    }
    if (p < e1) {
        long long r0 = __builtin_nontemporal_load(cn + p);
        uint4 u0 = base[(size_t)(unsigned)r0 * LPR];
        hacc8(acc, u0, __int_as_float((int)(r0 >> 32)));
    }
    #pragma unroll
    for (int off = 32; off >= LPR; off >>= 1) {
        #pragma unroll
        for (int j = 0; j < 8; ++j) acc[j] += __shfl_xor(acc[j], off);
    }
    if (slot == 0) {
        if (BR) {
            #pragma unroll
            for (int j = 0; j < 8; ++j)
                acc[j] = fmaxf(acc[j] + bias[l * 8 + j], 0.f);
        }
        f4 lo = {acc[0], acc[1], acc[2], acc[3]};
        f4 hi = {acc[4], acc[5], acc[6], acc[7]};
        float* o = out + (size_t)node * F + l * 8;
        __builtin_nontemporal_store(lo, (f4*)o);
        __builtin_nontemporal_store(hi, (f4*)(o + 4));
    }
}

// F=1 aggregation for the attention scalar
__global__ void agg1_kernel(const float* __restrict__ tin, const float* __restrict__ bias,
        const float* __restrict__ dinv, const int* __restrict__ rp,
        const long long* __restrict__ cn, float* __restrict__ out, int n) {
    int i = blockIdx.x * 256 + threadIdx.x;
    if (i >= n) return;
    float di = dinv[i];
    float acc = di * di * tin[i];
    int e0 = rp[i], e1 = rp[i + 1];
    int p = e0;
    float a0 = 0.f, a1 = 0.f, a2 = 0.f, a3 = 0.f;
    for (; p + 3 < e1; p += 4) {
        long long r0 = __builtin_nontemporal_load(cn + p);
        long long r1 = __builtin_nontemporal_load(cn + p + 1);
        long long r2 = __builtin_nontemporal_load(cn + p + 2);
        long long r3 = __builtin_nontemporal_load(cn + p + 3);
        a0 += __int_as_float((int)(r0 >> 32)) * tin[(int)(unsigned)r0];
        a1 += __int_as_float((int)(r1 >> 32)) * tin[(int)(unsigned)r1];
        a2 += __int_as_float((int)(r2 >> 32)) * tin[(int)(unsigned)r2];
        a3 += __int_as_float((int)(r3 >> 32)) * tin[(int)(unsigned)r3];
    }
    for (; p < e1; ++p) {
        long long r0 = __builtin_nontemporal_load(cn + p);
        a0 += __int_as_float((int)(r0 >> 32)) * tin[(int)(unsigned)r0];
    }
    acc += a0 + a1 + a2 + a3 + bias[0];
    out[i] = acc > 0.f ? acc : 0.f;
}

// ---------------- fused per-graph softmax (max + exp + sum) ----------------

__global__ __launch_bounds__(256) void smexp_kernel(const float* __restrict__ w,
        const int* __restrict__ gstart, float* __restrict__ gsum,
        float* __restrict__ e) {
    const int g = blockIdx.x;
    const int a = gstart[g], b = gstart[g + 1];
    const int tid = threadIdx.x;
    __shared__ float red[4];
    float m = 0.f;                       // w >= 0 (post-relu)
    for (int i = a + tid; i < b; i += 256) m = fmaxf(m, w[i]);
    #pragma unroll
    for (int off = 32; off > 0; off >>= 1) m = fmaxf(m, __shfl_xor(m, off));
    if ((tid & 63) == 0) red[tid >> 6] = m;
    __syncthreads();
    m = fmaxf(fmaxf(red[0], red[1]), fmaxf(red[2], red[3]));
    float s = 0.f;
    for (int i = a + tid; i < b; i += 256) {
        float ex = expf(w[i] - m);
        e[i] = ex;
        s += ex;
    }
    #pragma unroll
    for (int off = 32; off > 0; off >>= 1) s += __shfl_xor(s, off);
    __syncthreads();
    if ((tid & 63) == 0) red[tid >> 6] = s;
    __syncthreads();
    if (tid == 0) gsum[g] = red[0] + red[1] + red[2] + red[3];
}

// ---------------- attention pooling ----------------

__global__ __launch_bounds__(128) void pool_kernel(const float* __restrict__ f3,
        const float* __restrict__ e, const float* __restrict__ gsum,
        const int* __restrict__ gstart, float* __restrict__ pooled) {
    constexpr int SPG = 64;
    const int g = blockIdx.x / SPG, s = blockIdx.x % SPG;
    const int a = gstart[g], bnd = gstart[g + 1];
    const int len = bnd - a;
    if (len <= 0) return;
    const int chunk = (len + SPG - 1) / SPG;
    const int lo = a + s * chunk;
    const int hi = min(lo + chunk, bnd);
    if (lo >= hi) return;
    const float inv = 1.f / (gsum[g] + 1e-16f);
    const int tid = threadIdx.x;
    const int lane4 = tid & 31;
    const int rs    = tid >> 5;
    f4 acc = {0.f, 0.f, 0.f, 0.f};
    for (int i = lo + rs; i < hi; i += 4) {
        float w = e[i] * inv;
        f4 v = *(const f4*)&f3[(size_t)i * FH + lane4 * 4];
        acc.x += w * v.x; acc.y += w * v.y;
        acc.z += w * v.z; acc.w += w * v.w;
    }
    acc.x += __shfl_xor(acc.x, 32);
    acc.y += __shfl_xor(acc.y, 32);
    acc.z += __shfl_xor(acc.z, 32);
    acc.w += __shfl_xor(acc.w, 32);
    __shared__ float sm[128];
    if (tid >= 64 && tid < 96) *(f4*)&sm[(tid - 64) * 4] = acc;
    __syncthreads();
    if (tid < 32) {
        f4 o = *(f4*)&sm[tid * 4];
        o.x += acc.x; o.y += acc.y; o.z += acc.z; o.w += acc.w;
        float* dst = &pooled[g * FH + tid * 4];
        atomicAdd(dst + 0, o.x);
        atomicAdd(dst + 1, o.y);
        atomicAdd(dst + 2, o.z);
        atomicAdd(dst + 3, o.w);
    }
}

// ---------------- MLP ----------------

__global__ __launch_bounds__(128) void mlp1_kernel(const float* __restrict__ pooled,
        const float* __restrict__ M1, const float* __restrict__ bm1,
        float* __restrict__ hidden) {
    __shared__ float pr[FH];
    int g = blockIdx.x, j = threadIdx.x;
    pr[j] = pooled[g * FH + j];
    __syncthreads();
    float acc = bm1[j];
    #pragma unroll 8
    for (int k = 0; k < FH; ++k) acc += pr[k] * M1[k * FH + j];
    hidden[g * FH + j] = acc > 0.f ? acc : 0.f;
}

__global__ __launch_bounds__(256) void mlp2_kernel(const float* __restrict__ hidden,
        const float* __restrict__ M2, const float* __restrict__ bm2,
        float* __restrict__ out) {
    __shared__ float hr[FH];
    int g = blockIdx.x, j = threadIdx.x;
    if (j < FH) hr[j] = hidden[g * FH + j];
    __syncthreads();
    float acc = bm2[j];
    #pragma unroll 8
    for (int k = 0; k < FH; ++k) acc += hr[k] * M2[k * DOUT + j];
    out[g * DOUT + j] = acc;
}

// ---------------------------------------------------------------------------

extern "C" void kernel_launch(void* const* d_in, const int* in_sizes, int n_in,
                              void* d_out, int out_size, void* d_ws, size_t ws_size,
                              hipStream_t stream) {
    const float* x   = (const float*)d_in[0];
    const int*   ei  = (const int*)d_in[1];
    const int*   batch = (const int*)d_in[2];
    const float* W1  = (const float*)d_in[3];
    const float* b1  = (const float*)d_in[4];
    const float* W2  = (const float*)d_in[5];
    const float* b2  = (const float*)d_in[6];
    const float* W3  = (const float*)d_in[7];
    const float* b3  = (const float*)d_in[8];
    const float* A1  = (const float*)d_in[9];
    const float* ba1 = (const float*)d_in[10];
    const float* A2  = (const float*)d_in[11];
    const float* ba2 = (const float*)d_in[12];
    const float* A3  = (const float*)d_in[13];
    const float* ba3 = (const float*)d_in[14];
    const float* M1  = (const float*)d_in[15];
    const float* bm1 = (const float*)d_in[16];
    const float* M2  = (const float*)d_in[17];
    const float* bm2 = (const float*)d_in[18];

    const int N = in_sizes[0] / DIN;
    const int E = in_sizes[1] / 2;
    const int G = out_size / DOUT;
    const int* src = ei;
    const int* dst = ei + E;
    float* out = (float*)d_out;

    // bucket shift: smallest s with ceil(N / 2^s) <= NBUK
    int shift = 12;
    while (((N + (1 << shift) - 1) >> shift) > NBUK) ++shift;

    // workspace carve (aliased; see lifetime notes)
    char* p = (char*)d_ws;
    auto alloc = [&](size_t bytes) -> void* {
        void* r = (void*)p;
        p += (bytes + 255) & ~(size_t)255;
        return r;
    };
    float* dinv  = (float*)alloc((size_t)N * 4);
    int*   cnt   = (int*)alloc((size_t)N * 4);
    int*   fillc = (int*)alloc((size_t)N * 4);
    int*   rp    = (int*)alloc((size_t)(N + 1) * 4);
    long long* cn = (long long*)alloc((size_t)E * 8);
    float* SY    = (float*)alloc((size_t)N * FH * 4);   // Y, then f3
    float* SA    = (float*)alloc((size_t)N * FH * 4);   // entries, then f1/f2
    __half* ST   = (__half*)alloc((size_t)N * FH * 2);  // t2, then t3 (fp16)
    char*  SX    = (char*)alloc((size_t)N * 256);       // xh (fp16), then a1 (fp32 [N,64])
    __half* u2   = (__half*)alloc((size_t)N * 32 * 2);
    float* a2    = (float*)alloc((size_t)N * 32 * 4);
    float* wlin  = (float*)alloc((size_t)N * 4);
    float* wact  = (float*)alloc((size_t)N * 4);
    float* ebuf  = (float*)alloc((size_t)N * 4);
    float* gsum  = (float*)alloc((size_t)G * 4);
    int*   gstart= (int*)alloc((size_t)(G + 1) * 4);
    float* pooled= (float*)alloc((size_t)G * FH * 4);
    float* hidden= (float*)alloc((size_t)G * FH * 4);
    int*   bsum  = (int*)alloc(256 * 4);
    int*   boff  = (int*)alloc(256 * 4);
    int*   bcur  = (int*)alloc(NBUK * 4);
    _Float16* WT = (_Float16*)alloc((size_t)118784 * 2); // split-fp16 weights

    __half* xh = (__half*)SX;   // [N,128] fp16 (dead after Y-agg)
    float*  a1 = (float*)SX;    // [N,64] fp32 (written after xh dead)
    unsigned long long* entries = (unsigned long long*)SA;  // E*8 <= N*FH*4; dead before f1

    hipMemsetAsync(cnt, 0, (size_t)N * 4, stream);
    hipMemsetAsync(fillc, 0, (size_t)N * 4, stream);
    hipMemsetAsync(pooled, 0, (size_t)G * FH * 4, stream);

    const int eb = (E + 255) / 256;
    const int nb = (N + 255) / 256;
    const int NB = (N + 511) / 512;

    wprep_kernel<<<232, 256, 0, stream>>>(W1, W2, W3, A1, A2, WT);
    hist_kernel<<<eb, 256, 0, stream>>>(dst, cnt, E);
    dinv_kernel<<<nb, 256, 0, stream>>>(cnt, dinv, N);
    scan1_kernel<<<NB, 256, 0, stream>>>(cnt, bsum, N);
    scan2_kernel<<<1, 64, 0, stream>>>(bsum, boff, rp + N, NB);
    scan3_kernel<<<NB, 256, 0, stream>>>(cnt, boff, rp, N);
    gstart_kernel<<<1, 128, 0, stream>>>(batch, gstart, rp, bcur, N, G, shift);

    // two-pass bucketed edge sort (replaces fill_kernel)
    ebucket_kernel<<<(E + 2047) / 2048, 256, 0, stream>>>(src, dst, bcur, entries, E, shift);
    esort_kernel<<<NBUK * 64, 256, 0, stream>>>(entries, rp, fillc, dinv, cn, N, shift);

    const long n8 = (long)N * FH / 8;
    cvt16_kernel<<<(int)((n8 + 255) / 256), 256, 0, stream>>>(x, xh, n8);

    const int gb64  = (N + 63) / 64;    // mgemm BM=64 grids
    const int gb128 = (N + 127) / 128;  // mgemm BM=128 grid (FOUT=32)
    const int agb = (N + 3) / 4;        // wave-per-node agg blocks

    // shared layer-1 aggregation: Y = A_hat x   (no bias, no relu)
    aggh_kernel<FH, false><<<agb, 256, 0, stream>>>(xh, nullptr, dinv, rp, cn, SY, N);

    // layer-1 linears from Y (bias+relu fused), MFMA split-fp16
    mgemm_kernel<FH, FH, 1><<<gb64, 256, 0, stream>>>(SY, WT, WT + 16384, b1, SA, N);           // f1
    mgemm_kernel<FH, 64, 1><<<gb64, 256, 0, stream>>>(SY, WT + 98304, WT + 106496, ba1, a1, N); // a1 (SY dead)

    // feature branch layers 2,3
    mgemm_kernel<FH, FH, 2><<<gb64, 256, 0, stream>>>(SA, WT + 32768, WT + 49152, nullptr, ST, N); // t2 fp16
    aggh_kernel<FH, true><<<agb, 256, 0, stream>>>(ST, b2, dinv, rp, cn, SA, N);                   // f2 (f1 dead)
    mgemm_kernel<FH, FH, 2><<<gb64, 256, 0, stream>>>(SA, WT + 65536, WT + 81920, nullptr, ST, N); // t3 fp16
    aggh_kernel<FH, true><<<agb, 256, 0, stream>>>(ST, b3, dinv, rp, cn, SY, N);                   // f3 -> SY

    // attention branch layers 2,3
    mgemm_kernel<64, 32, 2><<<gb128, 256, 0, stream>>>(a1, WT + 114688, WT + 116736, nullptr, u2, N); // u2 fp16
    aggh_kernel<32, true><<<agb, 256, 0, stream>>>(u2, ba2, dinv, rp, cn, a2, N);                     // a2
    a3_kernel<<<nb, 256, 0, stream>>>(a2, A3, wlin, N);
    agg1_kernel<<<nb, 256, 0, stream>>>(wlin, ba3, dinv, rp, cn, wact, N);

    // fused per-graph softmax + attention pooling
    smexp_kernel<<<G, 256, 0, stream>>>(wact, gstart, gsum, ebuf);
    pool_kernel<<<G * 64, 128, 0, stream>>>(SY, ebuf, gsum, gstart, pooled);

    // MLP
    mlp1_kernel<<<G, 128, 0, stream>>>(pooled, M1, bm1, hidden);
    mlp2_kernel<<<G, 256, 0, stream>>>(hidden, M2, bm2, out);
}

// Round 3
// 361.530 us; speedup vs baseline: 1.0575x; 1.0575x over previous
//
#include <hip/hip_runtime.h>
#include <hip/hip_fp16.h>
#include <math.h>

// ---------------------------------------------------------------------------
// GCN (3-layer feature + 3-layer attention) + segment softmax + attention
// pooling + MLP.
// R9: esort (40us, WRITE 33MB vs 6.4MB payload - random scatter still
//     partial-line-writes at L2) replaced by ecsr_kernel: one block per
//     512-node bucket, counting sort entirely in LDS (hist -> scan ->
//     scatter into 128KB LDS image) then CONTIGUOUS stream-out to cn.
//     Write amplification 1x by construction. fillc + its memset dropped.
// ---------------------------------------------------------------------------

#define DIN 128
#define FH  128
#define DOUT 256
#define NBUK 128
#define SUBN 512
#define IMGCAP 16384

typedef float f4 __attribute__((ext_vector_type(4)));
typedef float f32x4 __attribute__((ext_vector_type(4)));
typedef _Float16 h8v __attribute__((ext_vector_type(8)));
typedef _Float16 h4v __attribute__((ext_vector_type(4)));

// ---------------- graph prep ----------------

__global__ void hist_kernel(const int* __restrict__ dst, int* __restrict__ cnt, int E) {
    int e = blockIdx.x * 256 + threadIdx.x;
    if (e < E) atomicAdd(&cnt[dst[e]], 1);
}

__global__ void dinv_kernel(const int* __restrict__ cnt, float* __restrict__ dinv, int n) {
    int i = blockIdx.x * 256 + threadIdx.x;
    if (i < n) dinv[i] = rsqrtf((float)(cnt[i] + 1));   // +1 self loop
}

__global__ __launch_bounds__(256) void scan1_kernel(const int* __restrict__ cnt,
                                                    int* __restrict__ bsum, int n) {
    __shared__ int sm[256];
    int tid = threadIdx.x;
    int base = blockIdx.x * 512;
    int a = (base + tid < n) ? cnt[base + tid] : 0;
    int b = (base + 256 + tid < n) ? cnt[base + 256 + tid] : 0;
    sm[tid] = a + b;
    __syncthreads();
    for (int off = 128; off > 0; off >>= 1) {
        if (tid < off) sm[tid] += sm[tid + off];
        __syncthreads();
    }
    if (tid == 0) bsum[blockIdx.x] = sm[0];
}

__global__ void scan2_kernel(const int* __restrict__ bsum, int* __restrict__ boff,
                             int* __restrict__ rpN, int nb) {
    if (threadIdx.x == 0) {
        int run = 0;
        for (int i = 0; i < nb; ++i) { boff[i] = run; run += bsum[i]; }
        *rpN = run;
    }
}

__global__ __launch_bounds__(256) void scan3_kernel(const int* __restrict__ cnt,
        const int* __restrict__ boff, int* __restrict__ rp, int n) {
    __shared__ int sm[256];
    int tid = threadIdx.x;
    int base = blockIdx.x * 512;
    int i0 = base + 2 * tid;
    int c0 = (i0 < n) ? cnt[i0] : 0;
    int c1 = (i0 + 1 < n) ? cnt[i0 + 1] : 0;
    int ps = c0 + c1;
    sm[tid] = ps;
    __syncthreads();
    for (int off = 1; off < 256; off <<= 1) {
        int v = (tid >= off) ? sm[tid - off] : 0;
        __syncthreads();
        sm[tid] += v;
        __syncthreads();
    }
    int excl = sm[tid] - ps + boff[blockIdx.x];
    if (i0 < n) rp[i0] = excl;
    if (i0 + 1 < n) rp[i0 + 1] = excl + c0;
}

// Pass A: bin edges into NBUK dst-range buckets. Per-block LDS histogram ->
// one global atomic per (block,bucket) -> contiguous frontier appends.
// Invariant: bcur[b] starts at rp[b<<shift], so bucket b's entries end up
// exactly in entries[rp[n0] .. rp[n1]) (unordered within).
__global__ __launch_bounds__(256) void ebucket_kernel(const int* __restrict__ src,
        const int* __restrict__ dst, int* __restrict__ bcur,
        unsigned long long* __restrict__ entries, int E, int shift) {
    __shared__ int lcnt[NBUK], lbase[NBUK], lcur[NBUK];
    const int tid = threadIdx.x;
    const int e0 = blockIdx.x * 2048;
    if (tid < NBUK) lcnt[tid] = 0;
    __syncthreads();
    int s_[8], d_[8];
    #pragma unroll
    for (int k = 0; k < 8; ++k) {
        int e = e0 + k * 256 + tid;
        if (e < E) {
            s_[k] = src[e];
            d_[k] = dst[e];
            atomicAdd(&lcnt[d_[k] >> shift], 1);
        } else {
            d_[k] = -1;
        }
    }
    __syncthreads();
    if (tid < NBUK) {
        lbase[tid] = lcnt[tid] ? atomicAdd(&bcur[tid], lcnt[tid]) : 0;
        lcur[tid] = 0;
    }
    __syncthreads();
    #pragma unroll
    for (int k = 0; k < 8; ++k) {
        if (d_[k] >= 0) {
            int b = d_[k] >> shift;
            int idx = atomicAdd(&lcur[b], 1);
            entries[(size_t)(lbase[b] + idx)] =
                ((unsigned long long)(unsigned)d_[k] << 32) | (unsigned)s_[k];
        }
    }
}

// Pass B: per-bucket counting sort fully in LDS, contiguous stream-out.
// One block per bucket (<=512 nodes, ~8.2K entries avg, IMGCAP=16K safe to
// +90 sigma; fallback scatters direct if ever exceeded).
__global__ __launch_bounds__(512) void ecsr_kernel(
        const unsigned long long* __restrict__ entries,
        const int* __restrict__ rp, const float* __restrict__ dinv,
        long long* __restrict__ cn, int n, int shift) {
    __shared__ long long img[IMGCAP];
    __shared__ int hist[SUBN];
    __shared__ int lcur[SUBN];
    __shared__ int sm[SUBN];
    __shared__ float dl[SUBN];
    const int b = blockIdx.x;
    const int n0 = b << shift;
    if (n0 >= n) return;
    const int n1 = min(n0 + (1 << shift), n);
    const int base = rp[n0];
    const int len  = rp[n1] - base;
    const int tid = threadIdx.x;
    hist[tid] = 0;
    lcur[tid] = 0;
    if (n0 + tid < n1) dl[tid] = dinv[n0 + tid];
    __syncthreads();
    // count
    for (int i = base + tid; i < base + len; i += 512)
        atomicAdd(&hist[(int)(entries[i] >> 32) - n0], 1);
    __syncthreads();
    // exclusive scan over SUBN counters (Hillis-Steele)
    int v = hist[tid];
    sm[tid] = v;
    __syncthreads();
    for (int off = 1; off < SUBN; off <<= 1) {
        int t = (tid >= off) ? sm[tid - off] : 0;
        __syncthreads();
        sm[tid] += t;
        __syncthreads();
    }
    hist[tid] = sm[tid] - v;
    __syncthreads();
    // scatter into LDS image (or direct fallback if oversized bucket)
    const bool fits = (len <= IMGCAP);
    for (int i = base + tid; i < base + len; i += 512) {
        unsigned long long e = entries[i];
        int d  = (int)(e >> 32) - n0;
        int sx = (int)(unsigned)(e & 0xffffffffu);
        int pos = hist[d] + atomicAdd(&lcur[d], 1);
        float w = dinv[sx] * dl[d];
        long long val = (long long)(unsigned)sx | ((long long)__float_as_int(w) << 32);
        if (fits) img[pos] = val;
        else      cn[base + pos] = val;
    }
    __syncthreads();
    if (fits)
        for (int i = tid; i < len; i += 512) cn[base + i] = img[i];
}

// gstart (binary search per graph) + bucket cursor init (needs rp).
__global__ void gstart_kernel(const int* __restrict__ batch, int* __restrict__ gstart,
                              const int* __restrict__ rp, int* __restrict__ bcur,
                              int n, int g, int shift) {
    int t = threadIdx.x;
    if (t < NBUK) bcur[t] = rp[min(t << shift, n)];
    if (t > g) return;
    int lo = 0, hi = n;
    while (lo < hi) {
        int mid = (lo + hi) >> 1;
        if (batch[mid] < t) lo = mid + 1; else hi = mid;
    }
    gstart[t] = lo;
}

// fp32 -> fp16 convert (8 elems / thread)
__global__ void cvt16_kernel(const float* __restrict__ in, __half* __restrict__ outh,
                             long n8) {
    long i = (long)blockIdx.x * 256 + threadIdx.x;
    if (i >= n8) return;
    f4 a = ((const f4*)in)[2 * i];
    f4 b = ((const f4*)in)[2 * i + 1];
    __half2 h0 = __float22half2_rn(make_float2(a.x, a.y));
    __half2 h1 = __float22half2_rn(make_float2(a.z, a.w));
    __half2 h2 = __float22half2_rn(make_float2(b.x, b.y));
    __half2 h3 = __float22half2_rn(make_float2(b.z, b.w));
    uint4 st;
    st.x = *(unsigned*)&h0; st.y = *(unsigned*)&h1;
    st.z = *(unsigned*)&h2; st.w = *(unsigned*)&h3;
    ((uint4*)outh)[i] = st;
}

// ---------------- weight prep: split-fp16 transpose ----------------

__device__ __forceinline__ void wsplit(const float* __restrict__ W,
        _Float16* __restrict__ Th, _Float16* __restrict__ Tl,
        int fin, int fout, int i) {
    int r = i / fout, c = i % fout;
    float w = W[i];
    _Float16 h = (_Float16)w;
    Th[c * fin + r] = h;
    Tl[c * fin + r] = (_Float16)(w - (float)h);
}

// WT half-offsets: W1h=0 W1l=16384 W2h=32768 W2l=49152 W3h=65536 W3l=81920
//                  A1h=98304 A1l=106496 A2h=114688 A2l=116736  (total 118784)
__global__ __launch_bounds__(256) void wprep_kernel(const float* __restrict__ W1,
        const float* __restrict__ W2, const float* __restrict__ W3,
        const float* __restrict__ A1, const float* __restrict__ A2,
        _Float16* __restrict__ T) {
    int i = blockIdx.x * 256 + threadIdx.x;
    if (i < 16384)       wsplit(W1, T,          T + 16384,  128, 128, i);
    else if (i < 32768)  wsplit(W2, T + 32768,  T + 49152,  128, 128, i - 16384);
    else if (i < 49152)  wsplit(W3, T + 65536,  T + 81920,  128, 128, i - 32768);
    else if (i < 57344)  wsplit(A1, T + 98304,  T + 106496, 128, 64,  i - 49152);
    else if (i < 59392)  wsplit(A2, T + 114688, T + 116736, 64,  32,  i - 57344);
}

// ---------------- MFMA dense linear: C = A[n,FIN] @ W[FIN,FOUT] ----------
// Split-fp16: acc = Ah*Wh + Ah*Wl + Al*Wh (fp32 MFMA accumulate).
// OMODE: 1 = fp32 out + bias + relu, 2 = fp16 out (no bias).

template<int FIN, int FOUT, int OMODE>
__global__ __launch_bounds__(256) void mgemm_kernel(const float* __restrict__ A,
        const _Float16* __restrict__ Wh, const _Float16* __restrict__ Wl,
        const float* __restrict__ bias, void* __restrict__ Cv, int n) {
    constexpr int NWC  = (FOUT / 16 < 4) ? FOUT / 16 : 4;  // waves across cols
    constexpr int NWR  = 4 / NWC;                          // waves across rows
    constexpr int BM   = 64 * NWR;                         // rows per block
    constexpr int CT   = FOUT / 16 / NWC;                  // col tiles per wave
    constexpr int KS   = FIN / 32;                         // K steps
    constexpr int LSTR = FIN + 8;                          // LDS row stride (halfs)
    __shared__ _Float16 Ahs[BM * LSTR];
    __shared__ _Float16 Als[BM * LSTR];

    const int tid  = threadIdx.x;
    const int w    = tid >> 6;
    const int lane = tid & 63;
    const long row0 = (long)blockIdx.x * BM;

    // stage A tile -> LDS, split fp32 -> fp16 high/low
    for (int i = tid; i < BM * (FIN / 4); i += 256) {
        int r  = i / (FIN / 4);
        int c4 = i % (FIN / 4);
        long gr = row0 + r;
        float4 v = {0.f, 0.f, 0.f, 0.f};
        if (gr < n) v = *(const float4*)&A[gr * FIN + c4 * 4];
        _Float16 h0 = (_Float16)v.x, h1 = (_Float16)v.y;
        _Float16 h2 = (_Float16)v.z, h3 = (_Float16)v.w;
        h4v hh = {h0, h1, h2, h3};
        h4v ll = {(_Float16)(v.x - (float)h0), (_Float16)(v.y - (float)h1),
                  (_Float16)(v.z - (float)h2), (_Float16)(v.w - (float)h3)};
        *(h4v*)&Ahs[r * LSTR + c4 * 4] = hh;
        *(h4v*)&Als[r * LSTR + c4 * 4] = ll;
    }

    // B fragments (registers, L2-resident weight reads)
    const int wc = w % NWC;
    const int wr = w / NWC;
    const int colbase = wc * CT * 16;
    const int bk = (lane >> 4) * 8;
    h8v Bh[CT][KS], Bl[CT][KS];
    #pragma unroll
    for (int ct = 0; ct < CT; ++ct) {
        int c = colbase + ct * 16 + (lane & 15);
        #pragma unroll
        for (int kk = 0; kk < KS; ++kk) {
            Bh[ct][kk] = *(const h8v*)&Wh[(size_t)c * FIN + kk * 32 + bk];
            Bl[ct][kk] = *(const h8v*)&Wl[(size_t)c * FIN + kk * 32 + bk];
        }
    }

    __syncthreads();

    f32x4 acc[4][CT];
    #pragma unroll
    for (int rt = 0; rt < 4; ++rt)
        #pragma unroll
        for (int ct = 0; ct < CT; ++ct)
            acc[rt][ct] = (f32x4){0.f, 0.f, 0.f, 0.f};

    #pragma unroll
    for (int rt = 0; rt < 4; ++rt) {
        const int r = wr * 64 + rt * 16 + (lane & 15);
        #pragma unroll
        for (int kk = 0; kk < KS; ++kk) {
            h8v ah = *(const h8v*)&Ahs[r * LSTR + kk * 32 + bk];
            h8v al = *(const h8v*)&Als[r * LSTR + kk * 32 + bk];
            #pragma unroll
            for (int ct = 0; ct < CT; ++ct) {
                acc[rt][ct] = __builtin_amdgcn_mfma_f32_16x16x32_f16(
                    ah, Bh[ct][kk], acc[rt][ct], 0, 0, 0);
                acc[rt][ct] = __builtin_amdgcn_mfma_f32_16x16x32_f16(
                    ah, Bl[ct][kk], acc[rt][ct], 0, 0, 0);
                acc[rt][ct] = __builtin_amdgcn_mfma_f32_16x16x32_f16(
                    al, Bh[ct][kk], acc[rt][ct], 0, 0, 0);
            }
        }
    }

    // epilogue: C/D layout col = lane&15, row = (lane>>4)*4 + j  [verified]
    #pragma unroll
    for (int rt = 0; rt < 4; ++rt) {
        const long rbase = row0 + wr * 64 + rt * 16 + (lane >> 4) * 4;
        #pragma unroll
        for (int ct = 0; ct < CT; ++ct) {
            const int col = colbase + ct * 16 + (lane & 15);
            if (OMODE == 1) {
                const float bv = bias[col];
                #pragma unroll
                for (int j = 0; j < 4; ++j) {
                    long r = rbase + j;
                    if (r < n)
                        ((float*)Cv)[r * FOUT + col] = fmaxf(acc[rt][ct][j] + bv, 0.f);
                }
            } else {
                #pragma unroll
                for (int j = 0; j < 4; ++j) {
                    long r = rbase + j;
                    if (r < n)
                        ((__half*)Cv)[r * FOUT + col] = __float2half(acc[rt][ct][j]);
                }
            }
        }
    }
}

// final attention linear: [n,32] @ [32,1]
__global__ void a3_kernel(const float* __restrict__ A, const float* __restrict__ W,
                          float* __restrict__ out, int n) {
    int i = blockIdx.x * 256 + threadIdx.x;
    if (i >= n) return;
    const float4* a = (const float4*)(A + (size_t)i * 32);
    float acc = 0.f;
    #pragma unroll
    for (int q = 0; q < 8; ++q) {
        float4 v = a[q];
        float4 w = ((const float4*)W)[q];
        acc += v.x * w.x + v.y * w.y + v.z * w.z + v.w * w.w;
    }
    out[i] = acc;
}

// ---------------- fp16-gather aggregation ----------------

__device__ __forceinline__ void hacc8(float acc[8], uint4 u, float w) {
    __half2 h; float2 f;
    h = *(__half2*)&u.x; f = __half22float2(h); acc[0] += w * f.x; acc[1] += w * f.y;
    h = *(__half2*)&u.y; f = __half22float2(h); acc[2] += w * f.x; acc[3] += w * f.y;
    h = *(__half2*)&u.z; f = __half22float2(h); acc[4] += w * f.x; acc[5] += w * f.y;
    h = *(__half2*)&u.w; f = __half22float2(h); acc[6] += w * f.x; acc[7] += w * f.y;
}

template<int F, bool BR>
__global__ __launch_bounds__(256) void aggh_kernel(const __half* __restrict__ tin,
        const float* __restrict__ bias, const float* __restrict__ dinv,
        const int* __restrict__ rp, const long long* __restrict__ cn,
        float* __restrict__ out, int n) {
    constexpr int LPR   = F / 8;
    constexpr int SLOTS = 64 / LPR;
    const int lane = threadIdx.x & 63;
    const int node = blockIdx.x * 4 + (threadIdx.x >> 6);
    if (node >= n) return;
    const int l    = lane % LPR;
    const int slot = lane / LPR;
    const uint4* base = (const uint4*)tin + l;
    const int e0 = rp[node], e1 = rp[node + 1];
    float acc[8] = {0.f, 0.f, 0.f, 0.f, 0.f, 0.f, 0.f, 0.f};
    if (slot == 0) {
        float di = dinv[node];
        uint4 u = base[(size_t)node * LPR];
        hacc8(acc, u, di * di);
    }
    int p = e0 + slot;
    for (; p + 3 * SLOTS < e1; p += 4 * SLOTS) {
        long long r0 = __builtin_nontemporal_load(cn + p);
        long long r1 = __builtin_nontemporal_load(cn + p + SLOTS);
        long long r2 = __builtin_nontemporal_load(cn + p + 2 * SLOTS);
        long long r3 = __builtin_nontemporal_load(cn + p + 3 * SLOTS);
        uint4 u0 = base[(size_t)(unsigned)r0 * LPR];
        uint4 u1 = base[(size_t)(unsigned)r1 * LPR];
        uint4 u2 = base[(size_t)(unsigned)r2 * LPR];
        uint4 u3 = base[(size_t)(unsigned)r3 * LPR];
        hacc8(acc, u0, __int_as_float((int)(r0 >> 32)));
        hacc8(acc, u1, __int_as_float((int)(r1 >> 32)));
        hacc8(acc, u2, __int_as_float((int)(r2 >> 32)));
        hacc8(acc, u3, __int_as_float((int)(r3 >> 32)));
    }
    for (; p + SLOTS < e1; p += 2 * SLOTS) {
        long long r0 = __builtin_nontemporal_load(cn + p);
        long long r1 = __builtin_nontemporal_load(cn + p + SLOTS);
        uint4 u0 = base[(size_t)(unsigned)r0 * LPR];
        uint4 u1 = base[(size_t)(unsigned)r1 * LPR];
        hacc8(acc, u0, __int_as_float((int)(r0 >> 32)));
        hacc8(acc, u1, __int_as_float((int)(r1 >> 32)));
    }
    if (p < e1) {
        long long r0 = __builtin_nontemporal_load(cn + p);
        uint4 u0 = base[(size_t)(unsigned)r0 * LPR];
        hacc8(acc, u0, __int_as_float((int)(r0 >> 32)));
    }
    #pragma unroll
    for (int off = 32; off >= LPR; off >>= 1) {
        #pragma unroll
        for (int j = 0; j < 8; ++j) acc[j] += __shfl_xor(acc[j], off);
    }
    if (slot == 0) {
        if (BR) {
            #pragma unroll
            for (int j = 0; j < 8; ++j)
                acc[j] = fmaxf(acc[j] + bias[l * 8 + j], 0.f);
        }
        f4 lo = {acc[0], acc[1], acc[2], acc[3]};
        f4 hi = {acc[4], acc[5], acc[6], acc[7]};
        float* o = out + (size_t)node * F + l * 8;
        __builtin_nontemporal_store(lo, (f4*)o);
        __builtin_nontemporal_store(hi, (f4*)(o + 4));
    }
}

// F=1 aggregation for the attention scalar
__global__ void agg1_kernel(const float* __restrict__ tin, const float* __restrict__ bias,
        const float* __restrict__ dinv, const int* __restrict__ rp,
        const long long* __restrict__ cn, float* __restrict__ out, int n) {
    int i = blockIdx.x * 256 + threadIdx.x;
    if (i >= n) return;
    float di = dinv[i];
    float acc = di * di * tin[i];
    int e0 = rp[i], e1 = rp[i + 1];
    int p = e0;
    float a0 = 0.f, a1 = 0.f, a2 = 0.f, a3 = 0.f;
    for (; p + 3 < e1; p += 4) {
        long long r0 = __builtin_nontemporal_load(cn + p);
        long long r1 = __builtin_nontemporal_load(cn + p + 1);
        long long r2 = __builtin_nontemporal_load(cn + p + 2);
        long long r3 = __builtin_nontemporal_load(cn + p + 3);
        a0 += __int_as_float((int)(r0 >> 32)) * tin[(int)(unsigned)r0];
        a1 += __int_as_float((int)(r1 >> 32)) * tin[(int)(unsigned)r1];
        a2 += __int_as_float((int)(r2 >> 32)) * tin[(int)(unsigned)r2];
        a3 += __int_as_float((int)(r3 >> 32)) * tin[(int)(unsigned)r3];
    }
    for (; p < e1; ++p) {
        long long r0 = __builtin_nontemporal_load(cn + p);
        a0 += __int_as_float((int)(r0 >> 32)) * tin[(int)(unsigned)r0];
    }
    acc += a0 + a1 + a2 + a3 + bias[0];
    out[i] = acc > 0.f ? acc : 0.f;
}

// ---------------- fused per-graph softmax (max + exp + sum) ----------------

__global__ __launch_bounds__(256) void smexp_kernel(const float* __restrict__ w,
        const int* __restrict__ gstart, float* __restrict__ gsum,
        float* __restrict__ e) {
    const int g = blockIdx.x;
    const int a = gstart[g], b = gstart[g + 1];
    const int tid = threadIdx.x;
    __shared__ float red[4];
    float m = 0.f;                       // w >= 0 (post-relu)
    for (int i = a + tid; i < b; i += 256) m = fmaxf(m, w[i]);
    #pragma unroll
    for (int off = 32; off > 0; off >>= 1) m = fmaxf(m, __shfl_xor(m, off));
    if ((tid & 63) == 0) red[tid >> 6] = m;
    __syncthreads();
    m = fmaxf(fmaxf(red[0], red[1]), fmaxf(red[2], red[3]));
    float s = 0.f;
    for (int i = a + tid; i < b; i += 256) {
        float ex = expf(w[i] - m);
        e[i] = ex;
        s += ex;
    }
    #pragma unroll
    for (int off = 32; off > 0; off >>= 1) s += __shfl_xor(s, off);
    __syncthreads();
    if ((tid & 63) == 0) red[tid >> 6] = s;
    __syncthreads();
    if (tid == 0) gsum[g] = red[0] + red[1] + red[2] + red[3];
}

// ---------------- attention pooling ----------------

__global__ __launch_bounds__(128) void pool_kernel(const float* __restrict__ f3,
        const float* __restrict__ e, const float* __restrict__ gsum,
        const int* __restrict__ gstart, float* __restrict__ pooled) {
    constexpr int SPG = 64;
    const int g = blockIdx.x / SPG, s = blockIdx.x % SPG;
    const int a = gstart[g], bnd = gstart[g + 1];
    const int len = bnd - a;
    if (len <= 0) return;
    const int chunk = (len + SPG - 1) / SPG;
    const int lo = a + s * chunk;
    const int hi = min(lo + chunk, bnd);
    if (lo >= hi) return;
    const float inv = 1.f / (gsum[g] + 1e-16f);
    const int tid = threadIdx.x;
    const int lane4 = tid & 31;
    const int rs    = tid >> 5;
    f4 acc = {0.f, 0.f, 0.f, 0.f};
    for (int i = lo + rs; i < hi; i += 4) {
        float w = e[i] * inv;
        f4 v = *(const f4*)&f3[(size_t)i * FH + lane4 * 4];
        acc.x += w * v.x; acc.y += w * v.y;
        acc.z += w * v.z; acc.w += w * v.w;
    }
    acc.x += __shfl_xor(acc.x, 32);
    acc.y += __shfl_xor(acc.y, 32);
    acc.z += __shfl_xor(acc.z, 32);
    acc.w += __shfl_xor(acc.w, 32);
    __shared__ float sm[128];
    if (tid >= 64 && tid < 96) *(f4*)&sm[(tid - 64) * 4] = acc;
    __syncthreads();
    if (tid < 32) {
        f4 o = *(f4*)&sm[tid * 4];
        o.x += acc.x; o.y += acc.y; o.z += acc.z; o.w += acc.w;
        float* dst = &pooled[g * FH + tid * 4];
        atomicAdd(dst + 0, o.x);
        atomicAdd(dst + 1, o.y);
        atomicAdd(dst + 2, o.z);
        atomicAdd(dst + 3, o.w);
    }
}

// ---------------- MLP ----------------

__global__ __launch_bounds__(128) void mlp1_kernel(const float* __restrict__ pooled,
        const float* __restrict__ M1, const float* __restrict__ bm1,
        float* __restrict__ hidden) {
    __shared__ float pr[FH];
    int g = blockIdx.x, j = threadIdx.x;
    pr[j] = pooled[g * FH + j];
    __syncthreads();
    float acc = bm1[j];
    #pragma unroll 8
    for (int k = 0; k < FH; ++k) acc += pr[k] * M1[k * FH + j];
    hidden[g * FH + j] = acc > 0.f ? acc : 0.f;
}

__global__ __launch_bounds__(256) void mlp2_kernel(const float* __restrict__ hidden,
        const float* __restrict__ M2, const float* __restrict__ bm2,
        float* __restrict__ out) {
    __shared__ float hr[FH];
    int g = blockIdx.x, j = threadIdx.x;
    if (j < FH) hr[j] = hidden[g * FH + j];
    __syncthreads();
    float acc = bm2[j];
    #pragma unroll 8
    for (int k = 0; k < FH; ++k) acc += hr[k] * M2[k * DOUT + j];
    out[g * DOUT + j] = acc;
}

// ---------------------------------------------------------------------------

extern "C" void kernel_launch(void* const* d_in, const int* in_sizes, int n_in,
                              void* d_out, int out_size, void* d_ws, size_t ws_size,
                              hipStream_t stream) {
    const float* x   = (const float*)d_in[0];
    const int*   ei  = (const int*)d_in[1];
    const int*   batch = (const int*)d_in[2];
    const float* W1  = (const float*)d_in[3];
    const float* b1  = (const float*)d_in[4];
    const float* W2  = (const float*)d_in[5];
    const float* b2  = (const float*)d_in[6];
    const float* W3  = (const float*)d_in[7];
    const float* b3  = (const float*)d_in[8];
    const float* A1  = (const float*)d_in[9];
    const float* ba1 = (const float*)d_in[10];
    const float* A2  = (const float*)d_in[11];
    const float* ba2 = (const float*)d_in[12];
    const float* A3  = (const float*)d_in[13];
    const float* ba3 = (const float*)d_in[14];
    const float* M1  = (const float*)d_in[15];
    const float* bm1 = (const float*)d_in[16];
    const float* M2  = (const float*)d_in[17];
    const float* bm2 = (const float*)d_in[18];

    const int N = in_sizes[0] / DIN;
    const int E = in_sizes[1] / 2;
    const int G = out_size / DOUT;
    const int* src = ei;
    const int* dst = ei + E;
    float* out = (float*)d_out;

    // bucket shift: smallest s with ceil(N / 2^s) <= NBUK (=9 for N=50000;
    // ecsr assumes bucket node-range <= SUBN=512, i.e. shift==9 here)
    int shift = 9;
    while (((N + (1 << shift) - 1) >> shift) > NBUK) ++shift;
    const int nbuckets = (N + (1 << shift) - 1) >> shift;

    // workspace carve (aliased; see lifetime notes)
    char* p = (char*)d_ws;
    auto alloc = [&](size_t bytes) -> void* {
        void* r = (void*)p;
        p += (bytes + 255) & ~(size_t)255;
        return r;
    };
    float* dinv  = (float*)alloc((size_t)N * 4);
    int*   cnt   = (int*)alloc((size_t)N * 4);
    int*   rp    = (int*)alloc((size_t)(N + 1) * 4);
    long long* cn = (long long*)alloc((size_t)E * 8);
    float* SY    = (float*)alloc((size_t)N * FH * 4);   // Y, then f3
    float* SA    = (float*)alloc((size_t)N * FH * 4);   // entries, then f1/f2
    __half* ST   = (__half*)alloc((size_t)N * FH * 2);  // t2, then t3 (fp16)
    char*  SX    = (char*)alloc((size_t)N * 256);       // xh (fp16), then a1 (fp32 [N,64])
    __half* u2   = (__half*)alloc((size_t)N * 32 * 2);
    float* a2    = (float*)alloc((size_t)N * 32 * 4);
    float* wlin  = (float*)alloc((size_t)N * 4);
    float* wact  = (float*)alloc((size_t)N * 4);
    float* ebuf  = (float*)alloc((size_t)N * 4);
    float* gsum  = (float*)alloc((size_t)G * 4);
    int*   gstart= (int*)alloc((size_t)(G + 1) * 4);
    float* pooled= (float*)alloc((size_t)G * FH * 4);
    float* hidden= (float*)alloc((size_t)G * FH * 4);
    int*   bsum  = (int*)alloc(256 * 4);
    int*   boff  = (int*)alloc(256 * 4);
    int*   bcur  = (int*)alloc(NBUK * 4);
    _Float16* WT = (_Float16*)alloc((size_t)118784 * 2); // split-fp16 weights

    __half* xh = (__half*)SX;   // [N,128] fp16 (dead after Y-agg)
    float*  a1 = (float*)SX;    // [N,64] fp32 (written after xh dead)
    unsigned long long* entries = (unsigned long long*)SA;  // E*8 <= N*FH*4; dead before f1

    hipMemsetAsync(cnt, 0, (size_t)N * 4, stream);
    hipMemsetAsync(pooled, 0, (size_t)G * FH * 4, stream);

    const int eb = (E + 255) / 256;
    const int nb = (N + 255) / 256;
    const int NB = (N + 511) / 512;

    wprep_kernel<<<232, 256, 0, stream>>>(W1, W2, W3, A1, A2, WT);
    hist_kernel<<<eb, 256, 0, stream>>>(dst, cnt, E);
    dinv_kernel<<<nb, 256, 0, stream>>>(cnt, dinv, N);
    scan1_kernel<<<NB, 256, 0, stream>>>(cnt, bsum, N);
    scan2_kernel<<<1, 64, 0, stream>>>(bsum, boff, rp + N, NB);
    scan3_kernel<<<NB, 256, 0, stream>>>(cnt, boff, rp, N);
    gstart_kernel<<<1, 128, 0, stream>>>(batch, gstart, rp, bcur, N, G, shift);

    // two-pass bucketed edge sort -> CSR (cn), LDS-staged final scatter
    ebucket_kernel<<<(E + 2047) / 2048, 256, 0, stream>>>(src, dst, bcur, entries, E, shift);
    ecsr_kernel<<<nbuckets, 512, 0, stream>>>(entries, rp, dinv, cn, N, shift);

    const long n8 = (long)N * FH / 8;
    cvt16_kernel<<<(int)((n8 + 255) / 256), 256, 0, stream>>>(x, xh, n8);

    const int gb64  = (N + 63) / 64;    // mgemm BM=64 grids
    const int gb128 = (N + 127) / 128;  // mgemm BM=128 grid (FOUT=32)
    const int agb = (N + 3) / 4;        // wave-per-node agg blocks

    // shared layer-1 aggregation: Y = A_hat x   (no bias, no relu)
    aggh_kernel<FH, false><<<agb, 256, 0, stream>>>(xh, nullptr, dinv, rp, cn, SY, N);

    // layer-1 linears from Y (bias+relu fused), MFMA split-fp16
    mgemm_kernel<FH, FH, 1><<<gb64, 256, 0, stream>>>(SY, WT, WT + 16384, b1, SA, N);           // f1
    mgemm_kernel<FH, 64, 1><<<gb64, 256, 0, stream>>>(SY, WT + 98304, WT + 106496, ba1, a1, N); // a1 (SY dead)

    // feature branch layers 2,3
    mgemm_kernel<FH, FH, 2><<<gb64, 256, 0, stream>>>(SA, WT + 32768, WT + 49152, nullptr, ST, N); // t2 fp16
    aggh_kernel<FH, true><<<agb, 256, 0, stream>>>(ST, b2, dinv, rp, cn, SA, N);                   // f2 (f1 dead)
    mgemm_kernel<FH, FH, 2><<<gb64, 256, 0, stream>>>(SA, WT + 65536, WT + 81920, nullptr, ST, N); // t3 fp16
    aggh_kernel<FH, true><<<agb, 256, 0, stream>>>(ST, b3, dinv, rp, cn, SY, N);                   // f3 -> SY

    // attention branch layers 2,3
    mgemm_kernel<64, 32, 2><<<gb128, 256, 0, stream>>>(a1, WT + 114688, WT + 116736, nullptr, u2, N); // u2 fp16
    aggh_kernel<32, true><<<agb, 256, 0, stream>>>(u2, ba2, dinv, rp, cn, a2, N);                     // a2
    a3_kernel<<<nb, 256, 0, stream>>>(a2, A3, wlin, N);
    agg1_kernel<<<nb, 256, 0, stream>>>(wlin, ba3, dinv, rp, cn, wact, N);

    // fused per-graph softmax + attention pooling
    smexp_kernel<<<G, 256, 0, stream>>>(wact, gstart, gsum, ebuf);
    pool_kernel<<<G * 64, 128, 0, stream>>>(SY, ebuf, gsum, gstart, pooled);

    // MLP
    mlp1_kernel<<<G, 128, 0, stream>>>(pooled, M1, bm1, hidden);
    mlp2_kernel<<<G, 256, 0, stream>>>(hidden, M2, bm2, out);
}

// Round 4
// 332.674 us; speedup vs baseline: 1.1493x; 1.0867x over previous
//
#include <hip/hip_runtime.h>
#include <hip/hip_fp16.h>
#include <math.h>

// ---------------------------------------------------------------------------
// GCN (3-layer feature + 3-layer attention) + segment softmax + attention
// pooling + MLP.
// R10: launch/traffic dieting around the (structurally-limited) gathers:
//  - fusedl1_kernel: f1=relu(Y@W1+b1) -> t2=f1@W2 and a1=relu(Y@A1+ba1) ->
//    u2=a1@A2 chained in ONE kernel (f1/a1 tiles live in LDS as split-fp16).
//    Replaces 4 mgemm launches; saves ~103MB HBM round-trips.
//  - a3 (a2@A3) fused into the a2-aggregation epilogue -> writes wlin[N,1],
//    a2 buffer + a3_kernel gone.
//  - hist folded into ebucket (fixed-capacity bucket cursors, b*ECAP), dinv
//    folded into scan1.
// ---------------------------------------------------------------------------

#define DIN 128
#define FH  128
#define DOUT 256
#define NBUK 128
#define SUBN 512
#define IMGCAP 16384
#define ECAP 16384

typedef float f4 __attribute__((ext_vector_type(4)));
typedef float f32x4 __attribute__((ext_vector_type(4)));
typedef _Float16 h8v __attribute__((ext_vector_type(8)));
typedef _Float16 h4v __attribute__((ext_vector_type(4)));

// ---------------- graph prep ----------------

// scan1 also produces dinv (rsqrt of degree+1) since it already loads cnt.
__global__ __launch_bounds__(256) void scan1_kernel(const int* __restrict__ cnt,
        int* __restrict__ bsum, float* __restrict__ dinv, int n) {
    __shared__ int sm[256];
    int tid = threadIdx.x;
    int base = blockIdx.x * 512;
    int a = (base + tid < n) ? cnt[base + tid] : 0;
    int b = (base + 256 + tid < n) ? cnt[base + 256 + tid] : 0;
    if (base + tid < n)       dinv[base + tid]       = rsqrtf((float)(a + 1));
    if (base + 256 + tid < n) dinv[base + 256 + tid] = rsqrtf((float)(b + 1));
    sm[tid] = a + b;
    __syncthreads();
    for (int off = 128; off > 0; off >>= 1) {
        if (tid < off) sm[tid] += sm[tid + off];
        __syncthreads();
    }
    if (tid == 0) bsum[blockIdx.x] = sm[0];
}

__global__ void scan2_kernel(const int* __restrict__ bsum, int* __restrict__ boff,
                             int* __restrict__ rpN, int nb) {
    if (threadIdx.x == 0) {
        int run = 0;
        for (int i = 0; i < nb; ++i) { boff[i] = run; run += bsum[i]; }
        *rpN = run;
    }
}

__global__ __launch_bounds__(256) void scan3_kernel(const int* __restrict__ cnt,
        const int* __restrict__ boff, int* __restrict__ rp, int n) {
    __shared__ int sm[256];
    int tid = threadIdx.x;
    int base = blockIdx.x * 512;
    int i0 = base + 2 * tid;
    int c0 = (i0 < n) ? cnt[i0] : 0;
    int c1 = (i0 + 1 < n) ? cnt[i0 + 1] : 0;
    int ps = c0 + c1;
    sm[tid] = ps;
    __syncthreads();
    for (int off = 1; off < 256; off <<= 1) {
        int v = (tid >= off) ? sm[tid - off] : 0;
        __syncthreads();
        sm[tid] += v;
        __syncthreads();
    }
    int excl = sm[tid] - ps + boff[blockIdx.x];
    if (i0 < n) rp[i0] = excl;
    if (i0 + 1 < n) rp[i0 + 1] = excl + c0;
}

// Pass A: bin edges into NBUK dst-range buckets at fixed-capacity bases
// (bcur[b] starts at b*ECAP) + degree histogram (replaces hist_kernel).
__global__ __launch_bounds__(256) void ebucket_kernel(const int* __restrict__ src,
        const int* __restrict__ dst, int* __restrict__ bcur,
        unsigned long long* __restrict__ entries, int* __restrict__ cnt,
        int E, int shift) {
    __shared__ int lcnt[NBUK], lbase[NBUK], lcur[NBUK];
    const int tid = threadIdx.x;
    const int e0 = blockIdx.x * 2048;
    if (tid < NBUK) lcnt[tid] = 0;
    __syncthreads();
    int s_[8], d_[8];
    #pragma unroll
    for (int k = 0; k < 8; ++k) {
        int e = e0 + k * 256 + tid;
        if (e < E) {
            s_[k] = src[e];
            d_[k] = dst[e];
            atomicAdd(&lcnt[d_[k] >> shift], 1);
            atomicAdd(&cnt[d_[k]], 1);
        } else {
            d_[k] = -1;
        }
    }
    __syncthreads();
    if (tid < NBUK) {
        lbase[tid] = lcnt[tid] ? atomicAdd(&bcur[tid], lcnt[tid]) : 0;
        lcur[tid] = 0;
    }
    __syncthreads();
    #pragma unroll
    for (int k = 0; k < 8; ++k) {
        if (d_[k] >= 0) {
            int b = d_[k] >> shift;
            int idx = lbase[b] + atomicAdd(&lcur[b], 1);
            if (idx < (b + 1) * ECAP)   // capacity guard (never hit: 91 sigma)
                entries[(size_t)idx] =
                    ((unsigned long long)(unsigned)d_[k] << 32) | (unsigned)s_[k];
        }
    }
}

// Pass B: per-bucket counting sort fully in LDS, contiguous stream-out to cn.
__global__ __launch_bounds__(512) void ecsr_kernel(
        const unsigned long long* __restrict__ entries,
        const int* __restrict__ rp, const float* __restrict__ dinv,
        long long* __restrict__ cn, int n, int shift) {
    __shared__ long long img[IMGCAP];
    __shared__ int hist[SUBN];
    __shared__ int lcur[SUBN];
    __shared__ int sm[SUBN];
    __shared__ float dl[SUBN];
    const int b = blockIdx.x;
    const int n0 = b << shift;
    if (n0 >= n) return;
    const int n1 = min(n0 + (1 << shift), n);
    const int base = rp[n0];
    const int len  = rp[n1] - base;
    const size_t ebase = (size_t)b * ECAP;
    const int tid = threadIdx.x;
    hist[tid] = 0;
    lcur[tid] = 0;
    if (n0 + tid < n1) dl[tid] = dinv[n0 + tid];
    __syncthreads();
    for (int i = tid; i < len; i += 512)
        atomicAdd(&hist[(int)(entries[ebase + i] >> 32) - n0], 1);
    __syncthreads();
    int v = hist[tid];
    sm[tid] = v;
    __syncthreads();
    for (int off = 1; off < SUBN; off <<= 1) {
        int t = (tid >= off) ? sm[tid - off] : 0;
        __syncthreads();
        sm[tid] += t;
        __syncthreads();
    }
    hist[tid] = sm[tid] - v;
    __syncthreads();
    const bool fits = (len <= IMGCAP);
    for (int i = tid; i < len; i += 512) {
        unsigned long long e = entries[ebase + i];
        int d  = (int)(e >> 32) - n0;
        int sx = (int)(unsigned)(e & 0xffffffffu);
        int pos = hist[d] + atomicAdd(&lcur[d], 1);
        float w = dinv[sx] * dl[d];
        long long val = (long long)(unsigned)sx | ((long long)__float_as_int(w) << 32);
        if (fits) img[pos] = val;
        else      cn[base + pos] = val;
    }
    __syncthreads();
    if (fits)
        for (int i = tid; i < len; i += 512) cn[base + i] = img[i];
}

__global__ void gstart_kernel(const int* __restrict__ batch, int* __restrict__ gstart,
                              int n, int g) {
    int t = threadIdx.x;
    if (t > g) return;
    int lo = 0, hi = n;
    while (lo < hi) {
        int mid = (lo + hi) >> 1;
        if (batch[mid] < t) lo = mid + 1; else hi = mid;
    }
    gstart[t] = lo;
}

// fp32 -> fp16 convert (8 elems / thread)
__global__ void cvt16_kernel(const float* __restrict__ in, __half* __restrict__ outh,
                             long n8) {
    long i = (long)blockIdx.x * 256 + threadIdx.x;
    if (i >= n8) return;
    f4 a = ((const f4*)in)[2 * i];
    f4 b = ((const f4*)in)[2 * i + 1];
    __half2 h0 = __float22half2_rn(make_float2(a.x, a.y));
    __half2 h1 = __float22half2_rn(make_float2(a.z, a.w));
    __half2 h2 = __float22half2_rn(make_float2(b.x, b.y));
    __half2 h3 = __float22half2_rn(make_float2(b.z, b.w));
    uint4 st;
    st.x = *(unsigned*)&h0; st.y = *(unsigned*)&h1;
    st.z = *(unsigned*)&h2; st.w = *(unsigned*)&h3;
    ((uint4*)outh)[i] = st;
}

// ---------------- weight prep: split-fp16 transpose ----------------

__device__ __forceinline__ void wsplit(const float* __restrict__ W,
        _Float16* __restrict__ Th, _Float16* __restrict__ Tl,
        int fin, int fout, int i) {
    int r = i / fout, c = i % fout;
    float w = W[i];
    _Float16 h = (_Float16)w;
    Th[c * fin + r] = h;
    Tl[c * fin + r] = (_Float16)(w - (float)h);
}

// WT half-offsets: W1h=0 W1l=16384 W2h=32768 W2l=49152 W3h=65536 W3l=81920
//                  A1h=98304 A1l=106496 A2h=114688 A2l=116736  (total 118784)
__global__ __launch_bounds__(256) void wprep_kernel(const float* __restrict__ W1,
        const float* __restrict__ W2, const float* __restrict__ W3,
        const float* __restrict__ A1, const float* __restrict__ A2,
        _Float16* __restrict__ T, int* __restrict__ bcur) {
    int i = blockIdx.x * 256 + threadIdx.x;
    if (blockIdx.x == 0 && threadIdx.x < NBUK) bcur[threadIdx.x] = threadIdx.x * ECAP;
    if (i < 16384)       wsplit(W1, T,          T + 16384,  128, 128, i);
    else if (i < 32768)  wsplit(W2, T + 32768,  T + 49152,  128, 128, i - 16384);
    else if (i < 49152)  wsplit(W3, T + 65536,  T + 81920,  128, 128, i - 32768);
    else if (i < 57344)  wsplit(A1, T + 98304,  T + 106496, 128, 64,  i - 49152);
    else if (i < 59392)  wsplit(A2, T + 114688, T + 116736, 64,  32,  i - 57344);
}

// ---------------- fused layer-1 linears (split-fp16 MFMA) ----------------
// From Y (64-row tile in LDS h/l):
//   f1 = relu(Y@W1+b1) -> LDS -> t2 = f1@W2 (fp16 out)
//   a1 = relu(Y@A1+ba1) -> LDS -> u2 = a1@A2 (fp16 out)

__global__ __launch_bounds__(256) void fusedl1_kernel(const float* __restrict__ Y,
        const _Float16* __restrict__ T, const float* __restrict__ b1,
        const float* __restrict__ ba1, __half* __restrict__ t2,
        __half* __restrict__ u2, int n) {
    constexpr int LSTR  = 136;
    constexpr int LSTRB = 72;
    __shared__ _Float16 Yh[64 * LSTR], Yl[64 * LSTR];
    __shared__ _Float16 Fh[64 * LSTR], Fl[64 * LSTR];
    const int tid  = threadIdx.x;
    const int w    = tid >> 6;
    const int lane = tid & 63;
    const int bk   = (lane >> 4) * 8;
    const int cl   = lane & 15;
    const long row0 = (long)blockIdx.x * 64;

    // stage Y -> LDS, split fp32 -> fp16 h/l
    for (int i = tid; i < 64 * 32; i += 256) {
        int r = i >> 5, c4 = i & 31;
        long gr = row0 + r;
        float4 v = {0.f, 0.f, 0.f, 0.f};
        if (gr < n) v = *(const float4*)&Y[gr * 128 + c4 * 4];
        _Float16 h0 = (_Float16)v.x, h1 = (_Float16)v.y;
        _Float16 h2 = (_Float16)v.z, h3 = (_Float16)v.w;
        *(h4v*)&Yh[r * LSTR + c4 * 4] = (h4v){h0, h1, h2, h3};
        *(h4v*)&Yl[r * LSTR + c4 * 4] =
            (h4v){(_Float16)(v.x - (float)h0), (_Float16)(v.y - (float)h1),
                  (_Float16)(v.z - (float)h2), (_Float16)(v.w - (float)h3)};
    }
    __syncthreads();

    // ---- GEMM1a: f1 = relu(Y@W1+b1); wave w owns cols [w*32, w*32+32)
    {
        const _Float16* W1h = T;
        const _Float16* W1l = T + 16384;
        h8v Bh[2][4], Bl[2][4];
        #pragma unroll
        for (int ct = 0; ct < 2; ++ct) {
            int c = w * 32 + ct * 16 + cl;
            #pragma unroll
            for (int kk = 0; kk < 4; ++kk) {
                Bh[ct][kk] = *(const h8v*)&W1h[c * 128 + kk * 32 + bk];
                Bl[ct][kk] = *(const h8v*)&W1l[c * 128 + kk * 32 + bk];
            }
        }
        f32x4 acc[4][2];
        #pragma unroll
        for (int rt = 0; rt < 4; ++rt)
            #pragma unroll
            for (int ct = 0; ct < 2; ++ct) acc[rt][ct] = (f32x4){0.f,0.f,0.f,0.f};
        #pragma unroll
        for (int rt = 0; rt < 4; ++rt) {
            int r = rt * 16 + cl;
            #pragma unroll
            for (int kk = 0; kk < 4; ++kk) {
                h8v ah = *(const h8v*)&Yh[r * LSTR + kk * 32 + bk];
                h8v al = *(const h8v*)&Yl[r * LSTR + kk * 32 + bk];
                #pragma unroll
                for (int ct = 0; ct < 2; ++ct) {
                    acc[rt][ct] = __builtin_amdgcn_mfma_f32_16x16x32_f16(ah, Bh[ct][kk], acc[rt][ct], 0, 0, 0);
                    acc[rt][ct] = __builtin_amdgcn_mfma_f32_16x16x32_f16(ah, Bl[ct][kk], acc[rt][ct], 0, 0, 0);
                    acc[rt][ct] = __builtin_amdgcn_mfma_f32_16x16x32_f16(al, Bh[ct][kk], acc[rt][ct], 0, 0, 0);
                }
            }
        }
        // bias+relu, split-write f1 -> Fh/Fl
        #pragma unroll
        for (int rt = 0; rt < 4; ++rt) {
            int rowb = rt * 16 + (lane >> 4) * 4;
            #pragma unroll
            for (int ct = 0; ct < 2; ++ct) {
                int col = w * 32 + ct * 16 + cl;
                float bv = b1[col];
                #pragma unroll
                for (int j = 0; j < 4; ++j) {
                    float v = fmaxf(acc[rt][ct][j] + bv, 0.f);
                    _Float16 h = (_Float16)v;
                    Fh[(rowb + j) * LSTR + col] = h;
                    Fl[(rowb + j) * LSTR + col] = (_Float16)(v - (float)h);
                }
            }
        }
    }
    __syncthreads();

    // ---- GEMM2a: t2 = f1@W2 (fp16 out)
    {
        const _Float16* W2h = T + 32768;
        const _Float16* W2l = T + 49152;
        h8v Bh[2][4], Bl[2][4];
        #pragma unroll
        for (int ct = 0; ct < 2; ++ct) {
            int c = w * 32 + ct * 16 + cl;
            #pragma unroll
            for (int kk = 0; kk < 4; ++kk) {
                Bh[ct][kk] = *(const h8v*)&W2h[c * 128 + kk * 32 + bk];
                Bl[ct][kk] = *(const h8v*)&W2l[c * 128 + kk * 32 + bk];
            }
        }
        f32x4 acc[4][2];
        #pragma unroll
        for (int rt = 0; rt < 4; ++rt)
            #pragma unroll
            for (int ct = 0; ct < 2; ++ct) acc[rt][ct] = (f32x4){0.f,0.f,0.f,0.f};
        #pragma unroll
        for (int rt = 0; rt < 4; ++rt) {
            int r = rt * 16 + cl;
            #pragma unroll
            for (int kk = 0; kk < 4; ++kk) {
                h8v ah = *(const h8v*)&Fh[r * LSTR + kk * 32 + bk];
                h8v al = *(const h8v*)&Fl[r * LSTR + kk * 32 + bk];
                #pragma unroll
                for (int ct = 0; ct < 2; ++ct) {
                    acc[rt][ct] = __builtin_amdgcn_mfma_f32_16x16x32_f16(ah, Bh[ct][kk], acc[rt][ct], 0, 0, 0);
                    acc[rt][ct] = __builtin_amdgcn_mfma_f32_16x16x32_f16(ah, Bl[ct][kk], acc[rt][ct], 0, 0, 0);
                    acc[rt][ct] = __builtin_amdgcn_mfma_f32_16x16x32_f16(al, Bh[ct][kk], acc[rt][ct], 0, 0, 0);
                }
            }
        }
        __syncthreads();   // all Fh/Fl reads done; GEMM1b may overwrite below
        #pragma unroll
        for (int rt = 0; rt < 4; ++rt) {
            long rbase = row0 + rt * 16 + (lane >> 4) * 4;
            #pragma unroll
            for (int ct = 0; ct < 2; ++ct) {
                int col = w * 32 + ct * 16 + cl;
                #pragma unroll
                for (int j = 0; j < 4; ++j) {
                    long r = rbase + j;
                    if (r < n) t2[r * 128 + col] = __float2half(acc[rt][ct][j]);
                }
            }
        }
    }

    // ---- GEMM1b: a1 = relu(Y@A1+ba1); wave w owns cols [w*16, w*16+16)
    {
        const _Float16* A1h = T + 98304;
        const _Float16* A1l = T + 106496;
        int c = w * 16 + cl;
        h8v Bh[4], Bl[4];
        #pragma unroll
        for (int kk = 0; kk < 4; ++kk) {
            Bh[kk] = *(const h8v*)&A1h[c * 128 + kk * 32 + bk];
            Bl[kk] = *(const h8v*)&A1l[c * 128 + kk * 32 + bk];
        }
        f32x4 acc[4];
        #pragma unroll
        for (int rt = 0; rt < 4; ++rt) acc[rt] = (f32x4){0.f,0.f,0.f,0.f};
        #pragma unroll
        for (int rt = 0; rt < 4; ++rt) {
            int r = rt * 16 + cl;
            #pragma unroll
            for (int kk = 0; kk < 4; ++kk) {
                h8v ah = *(const h8v*)&Yh[r * LSTR + kk * 32 + bk];
                h8v al = *(const h8v*)&Yl[r * LSTR + kk * 32 + bk];
                acc[rt] = __builtin_amdgcn_mfma_f32_16x16x32_f16(ah, Bh[kk], acc[rt], 0, 0, 0);
                acc[rt] = __builtin_amdgcn_mfma_f32_16x16x32_f16(ah, Bl[kk], acc[rt], 0, 0, 0);
                acc[rt] = __builtin_amdgcn_mfma_f32_16x16x32_f16(al, Bh[kk], acc[rt], 0, 0, 0);
            }
        }
        // bias+relu, split-write a1 -> Fh/Fl (stride LSTRB)
        float bv = ba1[c];
        #pragma unroll
        for (int rt = 0; rt < 4; ++rt) {
            int rowb = rt * 16 + (lane >> 4) * 4;
            #pragma unroll
            for (int j = 0; j < 4; ++j) {
                float v = fmaxf(acc[rt][j] + bv, 0.f);
                _Float16 h = (_Float16)v;
                Fh[(rowb + j) * LSTRB + c] = h;
                Fl[(rowb + j) * LSTRB + c] = (_Float16)(v - (float)h);
            }
        }
    }
    __syncthreads();

    // ---- GEMM2b: u2 = a1@A2 (fp16 out); waves 0,1 cover 32 cols
    if (w < 2) {
        const _Float16* A2h = T + 114688;
        const _Float16* A2l = T + 116736;
        int c = w * 16 + cl;
        h8v Bh[2], Bl[2];
        #pragma unroll
        for (int kk = 0; kk < 2; ++kk) {
            Bh[kk] = *(const h8v*)&A2h[c * 64 + kk * 32 + bk];
            Bl[kk] = *(const h8v*)&A2l[c * 64 + kk * 32 + bk];
        }
        f32x4 acc[4];
        #pragma unroll
        for (int rt = 0; rt < 4; ++rt) acc[rt] = (f32x4){0.f,0.f,0.f,0.f};
        #pragma unroll
        for (int rt = 0; rt < 4; ++rt) {
            int r = rt * 16 + cl;
            #pragma unroll
            for (int kk = 0; kk < 2; ++kk) {
                h8v ah = *(const h8v*)&Fh[r * LSTRB + kk * 32 + bk];
                h8v al = *(const h8v*)&Fl[r * LSTRB + kk * 32 + bk];
                acc[rt] = __builtin_amdgcn_mfma_f32_16x16x32_f16(ah, Bh[kk], acc[rt], 0, 0, 0);
                acc[rt] = __builtin_amdgcn_mfma_f32_16x16x32_f16(ah, Bl[kk], acc[rt], 0, 0, 0);
                acc[rt] = __builtin_amdgcn_mfma_f32_16x16x32_f16(al, Bh[kk], acc[rt], 0, 0, 0);
            }
        }
        #pragma unroll
        for (int rt = 0; rt < 4; ++rt) {
            long rbase = row0 + rt * 16 + (lane >> 4) * 4;
            #pragma unroll
            for (int j = 0; j < 4; ++j) {
                long r = rbase + j;
                if (r < n) u2[r * 32 + c] = __float2half(acc[rt][j]);
            }
        }
    }
}

// ---------------- MFMA dense linear (t3 only): C = A[n,128] @ W ----------
template<int FIN, int FOUT, int OMODE>
__global__ __launch_bounds__(256) void mgemm_kernel(const float* __restrict__ A,
        const _Float16* __restrict__ Wh, const _Float16* __restrict__ Wl,
        const float* __restrict__ bias, void* __restrict__ Cv, int n) {
    constexpr int NWC  = (FOUT / 16 < 4) ? FOUT / 16 : 4;
    constexpr int NWR  = 4 / NWC;
    constexpr int BM   = 64 * NWR;
    constexpr int CT   = FOUT / 16 / NWC;
    constexpr int KS   = FIN / 32;
    constexpr int LSTR = FIN + 8;
    __shared__ _Float16 Ahs[BM * LSTR];
    __shared__ _Float16 Als[BM * LSTR];

    const int tid  = threadIdx.x;
    const int w    = tid >> 6;
    const int lane = tid & 63;
    const long row0 = (long)blockIdx.x * BM;

    for (int i = tid; i < BM * (FIN / 4); i += 256) {
        int r  = i / (FIN / 4);
        int c4 = i % (FIN / 4);
        long gr = row0 + r;
        float4 v = {0.f, 0.f, 0.f, 0.f};
        if (gr < n) v = *(const float4*)&A[gr * FIN + c4 * 4];
        _Float16 h0 = (_Float16)v.x, h1 = (_Float16)v.y;
        _Float16 h2 = (_Float16)v.z, h3 = (_Float16)v.w;
        h4v hh = {h0, h1, h2, h3};
        h4v ll = {(_Float16)(v.x - (float)h0), (_Float16)(v.y - (float)h1),
                  (_Float16)(v.z - (float)h2), (_Float16)(v.w - (float)h3)};
        *(h4v*)&Ahs[r * LSTR + c4 * 4] = hh;
        *(h4v*)&Als[r * LSTR + c4 * 4] = ll;
    }

    const int wc = w % NWC;
    const int wr = w / NWC;
    const int colbase = wc * CT * 16;
    const int bk = (lane >> 4) * 8;
    h8v Bh[CT][KS], Bl[CT][KS];
    #pragma unroll
    for (int ct = 0; ct < CT; ++ct) {
        int c = colbase + ct * 16 + (lane & 15);
        #pragma unroll
        for (int kk = 0; kk < KS; ++kk) {
            Bh[ct][kk] = *(const h8v*)&Wh[(size_t)c * FIN + kk * 32 + bk];
            Bl[ct][kk] = *(const h8v*)&Wl[(size_t)c * FIN + kk * 32 + bk];
        }
    }

    __syncthreads();

    f32x4 acc[4][CT];
    #pragma unroll
    for (int rt = 0; rt < 4; ++rt)
        #pragma unroll
        for (int ct = 0; ct < CT; ++ct)
            acc[rt][ct] = (f32x4){0.f, 0.f, 0.f, 0.f};

    #pragma unroll
    for (int rt = 0; rt < 4; ++rt) {
        const int r = wr * 64 + rt * 16 + (lane & 15);
        #pragma unroll
        for (int kk = 0; kk < KS; ++kk) {
            h8v ah = *(const h8v*)&Ahs[r * LSTR + kk * 32 + bk];
            h8v al = *(const h8v*)&Als[r * LSTR + kk * 32 + bk];
            #pragma unroll
            for (int ct = 0; ct < CT; ++ct) {
                acc[rt][ct] = __builtin_amdgcn_mfma_f32_16x16x32_f16(ah, Bh[ct][kk], acc[rt][ct], 0, 0, 0);
                acc[rt][ct] = __builtin_amdgcn_mfma_f32_16x16x32_f16(ah, Bl[ct][kk], acc[rt][ct], 0, 0, 0);
                acc[rt][ct] = __builtin_amdgcn_mfma_f32_16x16x32_f16(al, Bh[ct][kk], acc[rt][ct], 0, 0, 0);
            }
        }
    }

    #pragma unroll
    for (int rt = 0; rt < 4; ++rt) {
        const long rbase = row0 + wr * 64 + rt * 16 + (lane >> 4) * 4;
        #pragma unroll
        for (int ct = 0; ct < CT; ++ct) {
            const int col = colbase + ct * 16 + (lane & 15);
            if (OMODE == 1) {
                const float bv = bias[col];
                #pragma unroll
                for (int j = 0; j < 4; ++j) {
                    long r = rbase + j;
                    if (r < n)
                        ((float*)Cv)[r * FOUT + col] = fmaxf(acc[rt][ct][j] + bv, 0.f);
                }
            } else {
                #pragma unroll
                for (int j = 0; j < 4; ++j) {
                    long r = rbase + j;
                    if (r < n)
                        ((__half*)Cv)[r * FOUT + col] = __float2half(acc[rt][ct][j]);
                }
            }
        }
    }
}

// ---------------- fp16-gather aggregation ----------------

__device__ __forceinline__ void hacc8(float acc[8], uint4 u, float w) {
    __half2 h; float2 f;
    h = *(__half2*)&u.x; f = __half22float2(h); acc[0] += w * f.x; acc[1] += w * f.y;
    h = *(__half2*)&u.y; f = __half22float2(h); acc[2] += w * f.x; acc[3] += w * f.y;
    h = *(__half2*)&u.z; f = __half22float2(h); acc[4] += w * f.x; acc[5] += w * f.y;
    h = *(__half2*)&u.w; f = __half22float2(h); acc[6] += w * f.x; acc[7] += w * f.y;
}

template<int F, bool BR>
__global__ __launch_bounds__(256) void aggh_kernel(const __half* __restrict__ tin,
        const float* __restrict__ bias, const float* __restrict__ dinv,
        const int* __restrict__ rp, const long long* __restrict__ cn,
        float* __restrict__ out, int n) {
    constexpr int LPR   = F / 8;
    constexpr int SLOTS = 64 / LPR;
    const int lane = threadIdx.x & 63;
    const int node = blockIdx.x * 4 + (threadIdx.x >> 6);
    if (node >= n) return;
    const int l    = lane % LPR;
    const int slot = lane / LPR;
    const uint4* base = (const uint4*)tin + l;
    const int e0 = rp[node], e1 = rp[node + 1];
    float acc[8] = {0.f, 0.f, 0.f, 0.f, 0.f, 0.f, 0.f, 0.f};
    if (slot == 0) {
        float di = dinv[node];
        uint4 u = base[(size_t)node * LPR];
        hacc8(acc, u, di * di);
    }
    int p = e0 + slot;
    for (; p + 3 * SLOTS < e1; p += 4 * SLOTS) {
        long long r0 = __builtin_nontemporal_load(cn + p);
        long long r1 = __builtin_nontemporal_load(cn + p + SLOTS);
        long long r2 = __builtin_nontemporal_load(cn + p + 2 * SLOTS);
        long long r3 = __builtin_nontemporal_load(cn + p + 3 * SLOTS);
        uint4 u0 = base[(size_t)(unsigned)r0 * LPR];
        uint4 u1 = base[(size_t)(unsigned)r1 * LPR];
        uint4 u2 = base[(size_t)(unsigned)r2 * LPR];
        uint4 u3 = base[(size_t)(unsigned)r3 * LPR];
        hacc8(acc, u0, __int_as_float((int)(r0 >> 32)));
        hacc8(acc, u1, __int_as_float((int)(r1 >> 32)));
        hacc8(acc, u2, __int_as_float((int)(r2 >> 32)));
        hacc8(acc, u3, __int_as_float((int)(r3 >> 32)));
    }
    for (; p + SLOTS < e1; p += 2 * SLOTS) {
        long long r0 = __builtin_nontemporal_load(cn + p);
        long long r1 = __builtin_nontemporal_load(cn + p + SLOTS);
        uint4 u0 = base[(size_t)(unsigned)r0 * LPR];
        uint4 u1 = base[(size_t)(unsigned)r1 * LPR];
        hacc8(acc, u0, __int_as_float((int)(r0 >> 32)));
        hacc8(acc, u1, __int_as_float((int)(r1 >> 32)));
    }
    if (p < e1) {
        long long r0 = __builtin_nontemporal_load(cn + p);
        uint4 u0 = base[(size_t)(unsigned)r0 * LPR];
        hacc8(acc, u0, __int_as_float((int)(r0 >> 32)));
    }
    #pragma unroll
    for (int off = 32; off >= LPR; off >>= 1) {
        #pragma unroll
        for (int j = 0; j < 8; ++j) acc[j] += __shfl_xor(acc[j], off);
    }
    if (slot == 0) {
        if (BR) {
            #pragma unroll
            for (int j = 0; j < 8; ++j)
                acc[j] = fmaxf(acc[j] + bias[l * 8 + j], 0.f);
        }
        f4 lo = {acc[0], acc[1], acc[2], acc[3]};
        f4 hi = {acc[4], acc[5], acc[6], acc[7]};
        float* o = out + (size_t)node * F + l * 8;
        __builtin_nontemporal_store(lo, (f4*)o);
        __builtin_nontemporal_store(hi, (f4*)(o + 4));
    }
}

// a2-aggregation (F=32) with fused a3 dot: wlin[node] = relu(agg+ba2) . A3
__global__ __launch_bounds__(256) void aggh32a_kernel(const __half* __restrict__ tin,
        const float* __restrict__ ba2, const float* __restrict__ A3,
        const float* __restrict__ dinv, const int* __restrict__ rp,
        const long long* __restrict__ cn, float* __restrict__ wlin, int n) {
    constexpr int LPR   = 4;
    constexpr int SLOTS = 16;
    const int lane = threadIdx.x & 63;
    const int node = blockIdx.x * 4 + (threadIdx.x >> 6);
    if (node >= n) return;
    const int l    = lane % LPR;
    const int slot = lane / LPR;
    const uint4* base = (const uint4*)tin + l;
    const int e0 = rp[node], e1 = rp[node + 1];
    float acc[8] = {0.f, 0.f, 0.f, 0.f, 0.f, 0.f, 0.f, 0.f};
    if (slot == 0) {
        float di = dinv[node];
        uint4 u = base[(size_t)node * LPR];
        hacc8(acc, u, di * di);
    }
    int p = e0 + slot;
    for (; p + SLOTS < e1; p += 2 * SLOTS) {
        long long r0 = __builtin_nontemporal_load(cn + p);
        long long r1 = __builtin_nontemporal_load(cn + p + SLOTS);
        uint4 u0 = base[(size_t)(unsigned)r0 * LPR];
        uint4 u1 = base[(size_t)(unsigned)r1 * LPR];
        hacc8(acc, u0, __int_as_float((int)(r0 >> 32)));
        hacc8(acc, u1, __int_as_float((int)(r1 >> 32)));
    }
    if (p < e1) {
        long long r0 = __builtin_nontemporal_load(cn + p);
        uint4 u0 = base[(size_t)(unsigned)r0 * LPR];
        hacc8(acc, u0, __int_as_float((int)(r0 >> 32)));
    }
    #pragma unroll
    for (int off = 32; off >= LPR; off >>= 1) {
        #pragma unroll
        for (int j = 0; j < 8; ++j) acc[j] += __shfl_xor(acc[j], off);
    }
    if (slot == 0) {
        float part = 0.f;
        #pragma unroll
        for (int j = 0; j < 8; ++j)
            part += fmaxf(acc[j] + ba2[l * 8 + j], 0.f) * A3[l * 8 + j];
        part += __shfl_xor(part, 1);
        part += __shfl_xor(part, 2);
        if (l == 0) wlin[node] = part;
    }
}

// F=1 aggregation for the attention scalar
__global__ void agg1_kernel(const float* __restrict__ tin, const float* __restrict__ bias,
        const float* __restrict__ dinv, const int* __restrict__ rp,
        const long long* __restrict__ cn, float* __restrict__ out, int n) {
    int i = blockIdx.x * 256 + threadIdx.x;
    if (i >= n) return;
    float di = dinv[i];
    float acc = di * di * tin[i];
    int e0 = rp[i], e1 = rp[i + 1];
    int p = e0;
    float a0 = 0.f, a1 = 0.f, a2 = 0.f, a3 = 0.f;
    for (; p + 3 < e1; p += 4) {
        long long r0 = __builtin_nontemporal_load(cn + p);
        long long r1 = __builtin_nontemporal_load(cn + p + 1);
        long long r2 = __builtin_nontemporal_load(cn + p + 2);
        long long r3 = __builtin_nontemporal_load(cn + p + 3);
        a0 += __int_as_float((int)(r0 >> 32)) * tin[(int)(unsigned)r0];
        a1 += __int_as_float((int)(r1 >> 32)) * tin[(int)(unsigned)r1];
        a2 += __int_as_float((int)(r2 >> 32)) * tin[(int)(unsigned)r2];
        a3 += __int_as_float((int)(r3 >> 32)) * tin[(int)(unsigned)r3];
    }
    for (; p < e1; ++p) {
        long long r0 = __builtin_nontemporal_load(cn + p);
        a0 += __int_as_float((int)(r0 >> 32)) * tin[(int)(unsigned)r0];
    }
    acc += a0 + a1 + a2 + a3 + bias[0];
    out[i] = acc > 0.f ? acc : 0.f;
}

// ---------------- fused per-graph softmax (max + exp + sum) ----------------

__global__ __launch_bounds__(256) void smexp_kernel(const float* __restrict__ w,
        const int* __restrict__ gstart, float* __restrict__ gsum,
        float* __restrict__ e) {
    const int g = blockIdx.x;
    const int a = gstart[g], b = gstart[g + 1];
    const int tid = threadIdx.x;
    __shared__ float red[4];
    float m = 0.f;                       // w >= 0 (post-relu)
    for (int i = a + tid; i < b; i += 256) m = fmaxf(m, w[i]);
    #pragma unroll
    for (int off = 32; off > 0; off >>= 1) m = fmaxf(m, __shfl_xor(m, off));
    if ((tid & 63) == 0) red[tid >> 6] = m;
    __syncthreads();
    m = fmaxf(fmaxf(red[0], red[1]), fmaxf(red[2], red[3]));
    float s = 0.f;
    for (int i = a + tid; i < b; i += 256) {
        float ex = expf(w[i] - m);
        e[i] = ex;
        s += ex;
    }
    #pragma unroll
    for (int off = 32; off > 0; off >>= 1) s += __shfl_xor(s, off);
    __syncthreads();
    if ((tid & 63) == 0) red[tid >> 6] = s;
    __syncthreads();
    if (tid == 0) gsum[g] = red[0] + red[1] + red[2] + red[3];
}

// ---------------- attention pooling ----------------

__global__ __launch_bounds__(128) void pool_kernel(const float* __restrict__ f3,
        const float* __restrict__ e, const float* __restrict__ gsum,
        const int* __restrict__ gstart, float* __restrict__ pooled) {
    constexpr int SPG = 64;
    const int g = blockIdx.x / SPG, s = blockIdx.x % SPG;
    const int a = gstart[g], bnd = gstart[g + 1];
    const int len = bnd - a;
    if (len <= 0) return;
    const int chunk = (len + SPG - 1) / SPG;
    const int lo = a + s * chunk;
    const int hi = min(lo + chunk, bnd);
    if (lo >= hi) return;
    const float inv = 1.f / (gsum[g] + 1e-16f);
    const int tid = threadIdx.x;
    const int lane4 = tid & 31;
    const int rs    = tid >> 5;
    f4 acc = {0.f, 0.f, 0.f, 0.f};
    for (int i = lo + rs; i < hi; i += 4) {
        float w = e[i] * inv;
        f4 v = *(const f4*)&f3[(size_t)i * FH + lane4 * 4];
        acc.x += w * v.x; acc.y += w * v.y;
        acc.z += w * v.z; acc.w += w * v.w;
    }
    acc.x += __shfl_xor(acc.x, 32);
    acc.y += __shfl_xor(acc.y, 32);
    acc.z += __shfl_xor(acc.z, 32);
    acc.w += __shfl_xor(acc.w, 32);
    __shared__ float sm[128];
    if (tid >= 64 && tid < 96) *(f4*)&sm[(tid - 64) * 4] = acc;
    __syncthreads();
    if (tid < 32) {
        f4 o = *(f4*)&sm[tid * 4];
        o.x += acc.x; o.y += acc.y; o.z += acc.z; o.w += acc.w;
        float* dst = &pooled[g * FH + tid * 4];
        atomicAdd(dst + 0, o.x);
        atomicAdd(dst + 1, o.y);
        atomicAdd(dst + 2, o.z);
        atomicAdd(dst + 3, o.w);
    }
}

// ---------------- MLP ----------------

__global__ __launch_bounds__(128) void mlp1_kernel(const float* __restrict__ pooled,
        const float* __restrict__ M1, const float* __restrict__ bm1,
        float* __restrict__ hidden) {
    __shared__ float pr[FH];
    int g = blockIdx.x, j = threadIdx.x;
    pr[j] = pooled[g * FH + j];
    __syncthreads();
    float acc = bm1[j];
    #pragma unroll 8
    for (int k = 0; k < FH; ++k) acc += pr[k] * M1[k * FH + j];
    hidden[g * FH + j] = acc > 0.f ? acc : 0.f;
}

__global__ __launch_bounds__(256) void mlp2_kernel(const float* __restrict__ hidden,
        const float* __restrict__ M2, const float* __restrict__ bm2,
        float* __restrict__ out) {
    __shared__ float hr[FH];
    int g = blockIdx.x, j = threadIdx.x;
    if (j < FH) hr[j] = hidden[g * FH + j];
    __syncthreads();
    float acc = bm2[j];
    #pragma unroll 8
    for (int k = 0; k < FH; ++k) acc += hr[k] * M2[k * DOUT + j];
    out[g * DOUT + j] = acc;
}

// ---------------------------------------------------------------------------

extern "C" void kernel_launch(void* const* d_in, const int* in_sizes, int n_in,
                              void* d_out, int out_size, void* d_ws, size_t ws_size,
                              hipStream_t stream) {
    const float* x   = (const float*)d_in[0];
    const int*   ei  = (const int*)d_in[1];
    const int*   batch = (const int*)d_in[2];
    const float* W1  = (const float*)d_in[3];
    const float* b1  = (const float*)d_in[4];
    const float* W2  = (const float*)d_in[5];
    const float* b2  = (const float*)d_in[6];
    const float* W3  = (const float*)d_in[7];
    const float* b3  = (const float*)d_in[8];
    const float* A1  = (const float*)d_in[9];
    const float* ba1 = (const float*)d_in[10];
    const float* A2  = (const float*)d_in[11];
    const float* ba2 = (const float*)d_in[12];
    const float* A3  = (const float*)d_in[13];
    const float* ba3 = (const float*)d_in[14];
    const float* M1  = (const float*)d_in[15];
    const float* bm1 = (const float*)d_in[16];
    const float* M2  = (const float*)d_in[17];
    const float* bm2 = (const float*)d_in[18];

    const int N = in_sizes[0] / DIN;
    const int E = in_sizes[1] / 2;
    const int G = out_size / DOUT;
    const int* src = ei;
    const int* dst = ei + E;
    float* out = (float*)d_out;

    // bucket shift: smallest s with ceil(N / 2^s) <= NBUK (=9 for N=50000)
    int shift = 9;
    while (((N + (1 << shift) - 1) >> shift) > NBUK) ++shift;
    const int nbuckets = (N + (1 << shift) - 1) >> shift;

    // workspace carve (aliased; see lifetime notes)
    char* p = (char*)d_ws;
    auto alloc = [&](size_t bytes) -> void* {
        void* r = (void*)p;
        p += (bytes + 255) & ~(size_t)255;
        return r;
    };
    float* dinv  = (float*)alloc((size_t)N * 4);
    int*   cnt   = (int*)alloc((size_t)N * 4);
    int*   rp    = (int*)alloc((size_t)(N + 1) * 4);
    long long* cn = (long long*)alloc((size_t)E * 8);
    float* SY    = (float*)alloc((size_t)N * FH * 4);   // Y, then f3
    float* SA    = (float*)alloc((size_t)N * FH * 4);   // entries, then f2
    __half* ST   = (__half*)alloc((size_t)N * FH * 2);  // t2, then t3 (fp16)
    char*  SX    = (char*)alloc((size_t)N * 256);       // xh (fp16)
    __half* u2   = (__half*)alloc((size_t)N * 32 * 2);
    float* wlin  = (float*)alloc((size_t)N * 4);
    float* wact  = (float*)alloc((size_t)N * 4);
    float* ebuf  = (float*)alloc((size_t)N * 4);
    float* gsum  = (float*)alloc((size_t)G * 4);
    int*   gstart= (int*)alloc((size_t)(G + 1) * 4);
    float* pooled= (float*)alloc((size_t)G * FH * 4);
    float* hidden= (float*)alloc((size_t)G * FH * 4);
    int*   bsum  = (int*)alloc(256 * 4);
    int*   boff  = (int*)alloc(256 * 4);
    int*   bcur  = (int*)alloc(NBUK * 4);
    _Float16* WT = (_Float16*)alloc((size_t)118784 * 2); // split-fp16 weights

    __half* xh = (__half*)SX;   // [N,128] fp16 (dead after Y-agg)
    unsigned long long* entries = (unsigned long long*)SA;  // NBUK*ECAP*8 = 16.8MB <= N*FH*4

    hipMemsetAsync(cnt, 0, (size_t)N * 4, stream);
    hipMemsetAsync(pooled, 0, (size_t)G * FH * 4, stream);

    const int nb = (N + 255) / 256;
    const int NB = (N + 511) / 512;

    wprep_kernel<<<232, 256, 0, stream>>>(W1, W2, W3, A1, A2, WT, bcur);
    // binning + degree histogram (replaces hist_kernel)
    ebucket_kernel<<<(E + 2047) / 2048, 256, 0, stream>>>(src, dst, bcur, entries, cnt, E, shift);
    scan1_kernel<<<NB, 256, 0, stream>>>(cnt, bsum, dinv, N);
    scan2_kernel<<<1, 64, 0, stream>>>(bsum, boff, rp + N, NB);
    scan3_kernel<<<NB, 256, 0, stream>>>(cnt, boff, rp, N);
    gstart_kernel<<<1, 128, 0, stream>>>(batch, gstart, N, G);
    ecsr_kernel<<<nbuckets, 512, 0, stream>>>(entries, rp, dinv, cn, N, shift);

    const long n8 = (long)N * FH / 8;
    cvt16_kernel<<<(int)((n8 + 255) / 256), 256, 0, stream>>>(x, xh, n8);

    const int gb64 = (N + 63) / 64;
    const int agb  = (N + 3) / 4;

    // shared layer-1 aggregation: Y = A_hat x
    aggh_kernel<FH, false><<<agb, 256, 0, stream>>>(xh, nullptr, dinv, rp, cn, SY, N);

    // fused layer-1+2 linears: Y -> t2 (ST), u2
    fusedl1_kernel<<<gb64, 256, 0, stream>>>(SY, WT, b1, ba1, (__half*)ST, u2, N);

    // feature branch
    aggh_kernel<FH, true><<<agb, 256, 0, stream>>>(ST, b2, dinv, rp, cn, SA, N);          // f2
    mgemm_kernel<FH, FH, 2><<<gb64, 256, 0, stream>>>(SA, WT + 65536, WT + 81920, nullptr, ST, N); // t3
    aggh_kernel<FH, true><<<agb, 256, 0, stream>>>(ST, b3, dinv, rp, cn, SY, N);          // f3 -> SY

    // attention branch: a2-agg with fused a3 dot -> wlin, then scalar agg
    aggh32a_kernel<<<agb, 256, 0, stream>>>(u2, ba2, A3, dinv, rp, cn, wlin, N);
    agg1_kernel<<<nb, 256, 0, stream>>>(wlin, ba3, dinv, rp, cn, wact, N);

    // fused per-graph softmax + attention pooling
    smexp_kernel<<<G, 256, 0, stream>>>(wact, gstart, gsum, ebuf);
    pool_kernel<<<G * 64, 128, 0, stream>>>(SY, ebuf, gsum, gstart, pooled);

    // MLP
    mlp1_kernel<<<G, 128, 0, stream>>>(pooled, M1, bm1, hidden);
    mlp2_kernel<<<G, 256, 0, stream>>>(hidden, M2, bm2, out);
}

// Round 5
// 309.895 us; speedup vs baseline: 1.2337x; 1.0735x over previous
//
#include <hip/hip_runtime.h>
#include <hip/hip_fp16.h>
#include <math.h>

// ---------------------------------------------------------------------------
// GCN (3-layer feature + 3-layer attention) + segment softmax + attention
// pooling + MLP.
// R11: ebucket (43.9us, WRITE 32MB vs 6.4MB payload) rebuilt:
//  - block-local counting sort in LDS (hist -> scan -> 16KB staged scatter)
//    then coalesced burst-out; partial-line frontier writebacks gone.
//  - 800K global cnt atomics replaced by ecount_kernel: per-bucket LDS
//    histogram of entries -> coalesced cnt writes. cnt memset dropped.
// ---------------------------------------------------------------------------

#define DIN 128
#define FH  128
#define DOUT 256
#define NBUK 128
#define SUBN 512
#define IMGCAP 16384
#define ECAP 16384

typedef float f4 __attribute__((ext_vector_type(4)));
typedef float f32x4 __attribute__((ext_vector_type(4)));
typedef _Float16 h8v __attribute__((ext_vector_type(8)));
typedef _Float16 h4v __attribute__((ext_vector_type(4)));

// ---------------- graph prep ----------------

// scan1 also produces dinv (rsqrt of degree+1) since it already loads cnt.
__global__ __launch_bounds__(256) void scan1_kernel(const int* __restrict__ cnt,
        int* __restrict__ bsum, float* __restrict__ dinv, int n) {
    __shared__ int sm[256];
    int tid = threadIdx.x;
    int base = blockIdx.x * 512;
    int a = (base + tid < n) ? cnt[base + tid] : 0;
    int b = (base + 256 + tid < n) ? cnt[base + 256 + tid] : 0;
    if (base + tid < n)       dinv[base + tid]       = rsqrtf((float)(a + 1));
    if (base + 256 + tid < n) dinv[base + 256 + tid] = rsqrtf((float)(b + 1));
    sm[tid] = a + b;
    __syncthreads();
    for (int off = 128; off > 0; off >>= 1) {
        if (tid < off) sm[tid] += sm[tid + off];
        __syncthreads();
    }
    if (tid == 0) bsum[blockIdx.x] = sm[0];
}

__global__ void scan2_kernel(const int* __restrict__ bsum, int* __restrict__ boff,
                             int* __restrict__ rpN, int nb) {
    if (threadIdx.x == 0) {
        int run = 0;
        for (int i = 0; i < nb; ++i) { boff[i] = run; run += bsum[i]; }
        *rpN = run;
    }
}

__global__ __launch_bounds__(256) void scan3_kernel(const int* __restrict__ cnt,
        const int* __restrict__ boff, int* __restrict__ rp, int n) {
    __shared__ int sm[256];
    int tid = threadIdx.x;
    int base = blockIdx.x * 512;
    int i0 = base + 2 * tid;
    int c0 = (i0 < n) ? cnt[i0] : 0;
    int c1 = (i0 + 1 < n) ? cnt[i0 + 1] : 0;
    int ps = c0 + c1;
    sm[tid] = ps;
    __syncthreads();
    for (int off = 1; off < 256; off <<= 1) {
        int v = (tid >= off) ? sm[tid - off] : 0;
        __syncthreads();
        sm[tid] += v;
        __syncthreads();
    }
    int excl = sm[tid] - ps + boff[blockIdx.x];
    if (i0 < n) rp[i0] = excl;
    if (i0 + 1 < n) rp[i0 + 1] = excl + c0;
}

// Pass A: block-local counting sort by bucket in LDS, then coalesced
// burst-out to per-bucket frontiers (bases at b*ECAP). Full lines are
// written back-to-back -> single writeback per line (no partial-line
// thrash). No global atomics except one bcur reserve per (block,bucket).
__global__ __launch_bounds__(256) void ebucket_kernel(const int* __restrict__ src,
        const int* __restrict__ dst, int* __restrict__ bcur,
        unsigned long long* __restrict__ entries, int E, int shift) {
    __shared__ int lcnt[NBUK], lscan[NBUK], lbase[NBUK], lcur[NBUK];
    __shared__ unsigned long long stage[2048];
    const int tid = threadIdx.x;
    const int e0 = blockIdx.x * 2048;
    if (tid < NBUK) { lcnt[tid] = 0; lcur[tid] = 0; }
    __syncthreads();
    int s_[8], d_[8];
    #pragma unroll
    for (int k = 0; k < 8; ++k) {
        int e = e0 + k * 256 + tid;
        if (e < E) {
            s_[k] = src[e];
            d_[k] = dst[e];
            atomicAdd(&lcnt[d_[k] >> shift], 1);
        } else {
            d_[k] = -1;
        }
    }
    __syncthreads();
    // exclusive scan over NBUK counters (Hillis-Steele, 128 lanes active)
    if (tid < NBUK) lscan[tid] = lcnt[tid];
    __syncthreads();
    for (int off = 1; off < NBUK; off <<= 1) {
        int v = 0;
        if (tid < NBUK && tid >= off) v = lscan[tid - off];
        __syncthreads();
        if (tid < NBUK) lscan[tid] += v;
        __syncthreads();
    }
    if (tid < NBUK) {
        lscan[tid] -= lcnt[tid];   // inclusive -> exclusive
        lbase[tid] = lcnt[tid] ? atomicAdd(&bcur[tid], lcnt[tid]) : 0;
    }
    __syncthreads();
    // scatter into LDS stage, sorted by bucket
    #pragma unroll
    for (int k = 0; k < 8; ++k) {
        if (d_[k] >= 0) {
            int b = d_[k] >> shift;
            int pos = lscan[b] + atomicAdd(&lcur[b], 1);
            stage[pos] = ((unsigned long long)(unsigned)d_[k] << 32) | (unsigned)s_[k];
        }
    }
    __syncthreads();
    // coalesced burst-out: LDS position i -> bucket via binary search
    const int total = min(2048, E - e0);
    for (int i = tid; i < total; i += 256) {
        int lo = 0, hi = NBUK - 1;
        while (lo < hi) {
            int mid = (lo + hi + 1) >> 1;
            if (lscan[mid] <= i) lo = mid; else hi = mid - 1;
        }
        int idx = lbase[lo] + (i - lscan[lo]);
        if (idx < (lo + 1) * ECAP)   // capacity guard (never hit: 91 sigma)
            entries[(size_t)idx] = stage[i];
    }
}

// Degree histogram from bucketed entries (replaces 800K global atomics):
// one block per bucket, LDS histogram, coalesced cnt write.
__global__ __launch_bounds__(512) void ecount_kernel(
        const unsigned long long* __restrict__ entries,
        const int* __restrict__ bcur, int* __restrict__ cnt, int n, int shift) {
    __shared__ int hist[SUBN];
    const int b = blockIdx.x;
    const int n0 = b << shift;
    if (n0 >= n) return;
    const int n1 = min(n0 + SUBN, n);
    const int tid = threadIdx.x;
    hist[tid] = 0;
    __syncthreads();
    const size_t ebase = (size_t)b * ECAP;
    const int len = min(bcur[b] - b * ECAP, ECAP);
    for (int i = tid; i < len; i += 512)
        atomicAdd(&hist[(int)(entries[ebase + i] >> 32) - n0], 1);
    __syncthreads();
    if (n0 + tid < n1) cnt[n0 + tid] = hist[tid];
}

// Pass B: per-bucket counting sort fully in LDS, contiguous stream-out to cn.
__global__ __launch_bounds__(512) void ecsr_kernel(
        const unsigned long long* __restrict__ entries,
        const int* __restrict__ rp, const float* __restrict__ dinv,
        long long* __restrict__ cn, int n, int shift) {
    __shared__ long long img[IMGCAP];
    __shared__ int hist[SUBN];
    __shared__ int lcur[SUBN];
    __shared__ int sm[SUBN];
    __shared__ float dl[SUBN];
    const int b = blockIdx.x;
    const int n0 = b << shift;
    if (n0 >= n) return;
    const int n1 = min(n0 + (1 << shift), n);
    const int base = rp[n0];
    const int len  = rp[n1] - base;
    const size_t ebase = (size_t)b * ECAP;
    const int tid = threadIdx.x;
    hist[tid] = 0;
    lcur[tid] = 0;
    if (n0 + tid < n1) dl[tid] = dinv[n0 + tid];
    __syncthreads();
    for (int i = tid; i < len; i += 512)
        atomicAdd(&hist[(int)(entries[ebase + i] >> 32) - n0], 1);
    __syncthreads();
    int v = hist[tid];
    sm[tid] = v;
    __syncthreads();
    for (int off = 1; off < SUBN; off <<= 1) {
        int t = (tid >= off) ? sm[tid - off] : 0;
        __syncthreads();
        sm[tid] += t;
        __syncthreads();
    }
    hist[tid] = sm[tid] - v;
    __syncthreads();
    const bool fits = (len <= IMGCAP);
    for (int i = tid; i < len; i += 512) {
        unsigned long long e = entries[ebase + i];
        int d  = (int)(e >> 32) - n0;
        int sx = (int)(unsigned)(e & 0xffffffffu);
        int pos = hist[d] + atomicAdd(&lcur[d], 1);
        float w = dinv[sx] * dl[d];
        long long val = (long long)(unsigned)sx | ((long long)__float_as_int(w) << 32);
        if (fits) img[pos] = val;
        else      cn[base + pos] = val;
    }
    __syncthreads();
    if (fits)
        for (int i = tid; i < len; i += 512) cn[base + i] = img[i];
}

__global__ void gstart_kernel(const int* __restrict__ batch, int* __restrict__ gstart,
                              int n, int g) {
    int t = threadIdx.x;
    if (t > g) return;
    int lo = 0, hi = n;
    while (lo < hi) {
        int mid = (lo + hi) >> 1;
        if (batch[mid] < t) lo = mid + 1; else hi = mid;
    }
    gstart[t] = lo;
}

// fp32 -> fp16 convert (8 elems / thread)
__global__ void cvt16_kernel(const float* __restrict__ in, __half* __restrict__ outh,
                             long n8) {
    long i = (long)blockIdx.x * 256 + threadIdx.x;
    if (i >= n8) return;
    f4 a = ((const f4*)in)[2 * i];
    f4 b = ((const f4*)in)[2 * i + 1];
    __half2 h0 = __float22half2_rn(make_float2(a.x, a.y));
    __half2 h1 = __float22half2_rn(make_float2(a.z, a.w));
    __half2 h2 = __float22half2_rn(make_float2(b.x, b.y));
    __half2 h3 = __float22half2_rn(make_float2(b.z, b.w));
    uint4 st;
    st.x = *(unsigned*)&h0; st.y = *(unsigned*)&h1;
    st.z = *(unsigned*)&h2; st.w = *(unsigned*)&h3;
    ((uint4*)outh)[i] = st;
}

// ---------------- weight prep: split-fp16 transpose ----------------

__device__ __forceinline__ void wsplit(const float* __restrict__ W,
        _Float16* __restrict__ Th, _Float16* __restrict__ Tl,
        int fin, int fout, int i) {
    int r = i / fout, c = i % fout;
    float w = W[i];
    _Float16 h = (_Float16)w;
    Th[c * fin + r] = h;
    Tl[c * fin + r] = (_Float16)(w - (float)h);
}

// WT half-offsets: W1h=0 W1l=16384 W2h=32768 W2l=49152 W3h=65536 W3l=81920
//                  A1h=98304 A1l=106496 A2h=114688 A2l=116736  (total 118784)
__global__ __launch_bounds__(256) void wprep_kernel(const float* __restrict__ W1,
        const float* __restrict__ W2, const float* __restrict__ W3,
        const float* __restrict__ A1, const float* __restrict__ A2,
        _Float16* __restrict__ T, int* __restrict__ bcur) {
    int i = blockIdx.x * 256 + threadIdx.x;
    if (blockIdx.x == 0 && threadIdx.x < NBUK) bcur[threadIdx.x] = threadIdx.x * ECAP;
    if (i < 16384)       wsplit(W1, T,          T + 16384,  128, 128, i);
    else if (i < 32768)  wsplit(W2, T + 32768,  T + 49152,  128, 128, i - 16384);
    else if (i < 49152)  wsplit(W3, T + 65536,  T + 81920,  128, 128, i - 32768);
    else if (i < 57344)  wsplit(A1, T + 98304,  T + 106496, 128, 64,  i - 49152);
    else if (i < 59392)  wsplit(A2, T + 114688, T + 116736, 64,  32,  i - 57344);
}

// ---------------- fused layer-1 linears (split-fp16 MFMA) ----------------
// From Y (64-row tile in LDS h/l):
//   f1 = relu(Y@W1+b1) -> LDS -> t2 = f1@W2 (fp16 out)
//   a1 = relu(Y@A1+ba1) -> LDS -> u2 = a1@A2 (fp16 out)

__global__ __launch_bounds__(256) void fusedl1_kernel(const float* __restrict__ Y,
        const _Float16* __restrict__ T, const float* __restrict__ b1,
        const float* __restrict__ ba1, __half* __restrict__ t2,
        __half* __restrict__ u2, int n) {
    constexpr int LSTR  = 136;
    constexpr int LSTRB = 72;
    __shared__ _Float16 Yh[64 * LSTR], Yl[64 * LSTR];
    __shared__ _Float16 Fh[64 * LSTR], Fl[64 * LSTR];
    const int tid  = threadIdx.x;
    const int w    = tid >> 6;
    const int lane = tid & 63;
    const int bk   = (lane >> 4) * 8;
    const int cl   = lane & 15;
    const long row0 = (long)blockIdx.x * 64;

    // stage Y -> LDS, split fp32 -> fp16 h/l
    for (int i = tid; i < 64 * 32; i += 256) {
        int r = i >> 5, c4 = i & 31;
        long gr = row0 + r;
        float4 v = {0.f, 0.f, 0.f, 0.f};
        if (gr < n) v = *(const float4*)&Y[gr * 128 + c4 * 4];
        _Float16 h0 = (_Float16)v.x, h1 = (_Float16)v.y;
        _Float16 h2 = (_Float16)v.z, h3 = (_Float16)v.w;
        *(h4v*)&Yh[r * LSTR + c4 * 4] = (h4v){h0, h1, h2, h3};
        *(h4v*)&Yl[r * LSTR + c4 * 4] =
            (h4v){(_Float16)(v.x - (float)h0), (_Float16)(v.y - (float)h1),
                  (_Float16)(v.z - (float)h2), (_Float16)(v.w - (float)h3)};
    }
    __syncthreads();

    // ---- GEMM1a: f1 = relu(Y@W1+b1); wave w owns cols [w*32, w*32+32)
    {
        const _Float16* W1h = T;
        const _Float16* W1l = T + 16384;
        h8v Bh[2][4], Bl[2][4];
        #pragma unroll
        for (int ct = 0; ct < 2; ++ct) {
            int c = w * 32 + ct * 16 + cl;
            #pragma unroll
            for (int kk = 0; kk < 4; ++kk) {
                Bh[ct][kk] = *(const h8v*)&W1h[c * 128 + kk * 32 + bk];
                Bl[ct][kk] = *(const h8v*)&W1l[c * 128 + kk * 32 + bk];
            }
        }
        f32x4 acc[4][2];
        #pragma unroll
        for (int rt = 0; rt < 4; ++rt)
            #pragma unroll
            for (int ct = 0; ct < 2; ++ct) acc[rt][ct] = (f32x4){0.f,0.f,0.f,0.f};
        #pragma unroll
        for (int rt = 0; rt < 4; ++rt) {
            int r = rt * 16 + cl;
            #pragma unroll
            for (int kk = 0; kk < 4; ++kk) {
                h8v ah = *(const h8v*)&Yh[r * LSTR + kk * 32 + bk];
                h8v al = *(const h8v*)&Yl[r * LSTR + kk * 32 + bk];
                #pragma unroll
                for (int ct = 0; ct < 2; ++ct) {
                    acc[rt][ct] = __builtin_amdgcn_mfma_f32_16x16x32_f16(ah, Bh[ct][kk], acc[rt][ct], 0, 0, 0);
                    acc[rt][ct] = __builtin_amdgcn_mfma_f32_16x16x32_f16(ah, Bl[ct][kk], acc[rt][ct], 0, 0, 0);
                    acc[rt][ct] = __builtin_amdgcn_mfma_f32_16x16x32_f16(al, Bh[ct][kk], acc[rt][ct], 0, 0, 0);
                }
            }
        }
        // bias+relu, split-write f1 -> Fh/Fl
        #pragma unroll
        for (int rt = 0; rt < 4; ++rt) {
            int rowb = rt * 16 + (lane >> 4) * 4;
            #pragma unroll
            for (int ct = 0; ct < 2; ++ct) {
                int col = w * 32 + ct * 16 + cl;
                float bv = b1[col];
                #pragma unroll
                for (int j = 0; j < 4; ++j) {
                    float v = fmaxf(acc[rt][ct][j] + bv, 0.f);
                    _Float16 h = (_Float16)v;
                    Fh[(rowb + j) * LSTR + col] = h;
                    Fl[(rowb + j) * LSTR + col] = (_Float16)(v - (float)h);
                }
            }
        }
    }
    __syncthreads();

    // ---- GEMM2a: t2 = f1@W2 (fp16 out)
    {
        const _Float16* W2h = T + 32768;
        const _Float16* W2l = T + 49152;
        h8v Bh[2][4], Bl[2][4];
        #pragma unroll
        for (int ct = 0; ct < 2; ++ct) {
            int c = w * 32 + ct * 16 + cl;
            #pragma unroll
            for (int kk = 0; kk < 4; ++kk) {
                Bh[ct][kk] = *(const h8v*)&W2h[c * 128 + kk * 32 + bk];
                Bl[ct][kk] = *(const h8v*)&W2l[c * 128 + kk * 32 + bk];
            }
        }
        f32x4 acc[4][2];
        #pragma unroll
        for (int rt = 0; rt < 4; ++rt)
            #pragma unroll
            for (int ct = 0; ct < 2; ++ct) acc[rt][ct] = (f32x4){0.f,0.f,0.f,0.f};
        #pragma unroll
        for (int rt = 0; rt < 4; ++rt) {
            int r = rt * 16 + cl;
            #pragma unroll
            for (int kk = 0; kk < 4; ++kk) {
                h8v ah = *(const h8v*)&Fh[r * LSTR + kk * 32 + bk];
                h8v al = *(const h8v*)&Fl[r * LSTR + kk * 32 + bk];
                #pragma unroll
                for (int ct = 0; ct < 2; ++ct) {
                    acc[rt][ct] = __builtin_amdgcn_mfma_f32_16x16x32_f16(ah, Bh[ct][kk], acc[rt][ct], 0, 0, 0);
                    acc[rt][ct] = __builtin_amdgcn_mfma_f32_16x16x32_f16(ah, Bl[ct][kk], acc[rt][ct], 0, 0, 0);
                    acc[rt][ct] = __builtin_amdgcn_mfma_f32_16x16x32_f16(al, Bh[ct][kk], acc[rt][ct], 0, 0, 0);
                }
            }
        }
        __syncthreads();   // all Fh/Fl reads done; GEMM1b may overwrite below
        #pragma unroll
        for (int rt = 0; rt < 4; ++rt) {
            long rbase = row0 + rt * 16 + (lane >> 4) * 4;
            #pragma unroll
            for (int ct = 0; ct < 2; ++ct) {
                int col = w * 32 + ct * 16 + cl;
                #pragma unroll
                for (int j = 0; j < 4; ++j) {
                    long r = rbase + j;
                    if (r < n) t2[r * 128 + col] = __float2half(acc[rt][ct][j]);
                }
            }
        }
    }

    // ---- GEMM1b: a1 = relu(Y@A1+ba1); wave w owns cols [w*16, w*16+16)
    {
        const _Float16* A1h = T + 98304;
        const _Float16* A1l = T + 106496;
        int c = w * 16 + cl;
        h8v Bh[4], Bl[4];
        #pragma unroll
        for (int kk = 0; kk < 4; ++kk) {
            Bh[kk] = *(const h8v*)&A1h[c * 128 + kk * 32 + bk];
            Bl[kk] = *(const h8v*)&A1l[c * 128 + kk * 32 + bk];
        }
        f32x4 acc[4];
        #pragma unroll
        for (int rt = 0; rt < 4; ++rt) acc[rt] = (f32x4){0.f,0.f,0.f,0.f};
        #pragma unroll
        for (int rt = 0; rt < 4; ++rt) {
            int r = rt * 16 + cl;
            #pragma unroll
            for (int kk = 0; kk < 4; ++kk) {
                h8v ah = *(const h8v*)&Yh[r * LSTR + kk * 32 + bk];
                h8v al = *(const h8v*)&Yl[r * LSTR + kk * 32 + bk];
                acc[rt] = __builtin_amdgcn_mfma_f32_16x16x32_f16(ah, Bh[kk], acc[rt], 0, 0, 0);
                acc[rt] = __builtin_amdgcn_mfma_f32_16x16x32_f16(ah, Bl[kk], acc[rt], 0, 0, 0);
                acc[rt] = __builtin_amdgcn_mfma_f32_16x16x32_f16(al, Bh[kk], acc[rt], 0, 0, 0);
            }
        }
        // bias+relu, split-write a1 -> Fh/Fl (stride LSTRB)
        float bv = ba1[c];
        #pragma unroll
        for (int rt = 0; rt < 4; ++rt) {
            int rowb = rt * 16 + (lane >> 4) * 4;
            #pragma unroll
            for (int j = 0; j < 4; ++j) {
                float v = fmaxf(acc[rt][j] + bv, 0.f);
                _Float16 h = (_Float16)v;
                Fh[(rowb + j) * LSTRB + c] = h;
                Fl[(rowb + j) * LSTRB + c] = (_Float16)(v - (float)h);
            }
        }
    }
    __syncthreads();

    // ---- GEMM2b: u2 = a1@A2 (fp16 out); waves 0,1 cover 32 cols
    if (w < 2) {
        const _Float16* A2h = T + 114688;
        const _Float16* A2l = T + 116736;
        int c = w * 16 + cl;
        h8v Bh[2], Bl[2];
        #pragma unroll
        for (int kk = 0; kk < 2; ++kk) {
            Bh[kk] = *(const h8v*)&A2h[c * 64 + kk * 32 + bk];
            Bl[kk] = *(const h8v*)&A2l[c * 64 + kk * 32 + bk];
        }
        f32x4 acc[4];
        #pragma unroll
        for (int rt = 0; rt < 4; ++rt) acc[rt] = (f32x4){0.f,0.f,0.f,0.f};
        #pragma unroll
        for (int rt = 0; rt < 4; ++rt) {
            int r = rt * 16 + cl;
            #pragma unroll
            for (int kk = 0; kk < 2; ++kk) {
                h8v ah = *(const h8v*)&Fh[r * LSTRB + kk * 32 + bk];
                h8v al = *(const h8v*)&Fl[r * LSTRB + kk * 32 + bk];
                acc[rt] = __builtin_amdgcn_mfma_f32_16x16x32_f16(ah, Bh[kk], acc[rt], 0, 0, 0);
                acc[rt] = __builtin_amdgcn_mfma_f32_16x16x32_f16(ah, Bl[kk], acc[rt], 0, 0, 0);
                acc[rt] = __builtin_amdgcn_mfma_f32_16x16x32_f16(al, Bh[kk], acc[rt], 0, 0, 0);
            }
        }
        #pragma unroll
        for (int rt = 0; rt < 4; ++rt) {
            long rbase = row0 + rt * 16 + (lane >> 4) * 4;
            #pragma unroll
            for (int j = 0; j < 4; ++j) {
                long r = rbase + j;
                if (r < n) u2[r * 32 + c] = __float2half(acc[rt][j]);
            }
        }
    }
}

// ---------------- MFMA dense linear (t3 only): C = A[n,128] @ W ----------
template<int FIN, int FOUT, int OMODE>
__global__ __launch_bounds__(256) void mgemm_kernel(const float* __restrict__ A,
        const _Float16* __restrict__ Wh, const _Float16* __restrict__ Wl,
        const float* __restrict__ bias, void* __restrict__ Cv, int n) {
    constexpr int NWC  = (FOUT / 16 < 4) ? FOUT / 16 : 4;
    constexpr int NWR  = 4 / NWC;
    constexpr int BM   = 64 * NWR;
    constexpr int CT   = FOUT / 16 / NWC;
    constexpr int KS   = FIN / 32;
    constexpr int LSTR = FIN + 8;
    __shared__ _Float16 Ahs[BM * LSTR];
    __shared__ _Float16 Als[BM * LSTR];

    const int tid  = threadIdx.x;
    const int w    = tid >> 6;
    const int lane = tid & 63;
    const long row0 = (long)blockIdx.x * BM;

    for (int i = tid; i < BM * (FIN / 4); i += 256) {
        int r  = i / (FIN / 4);
        int c4 = i % (FIN / 4);
        long gr = row0 + r;
        float4 v = {0.f, 0.f, 0.f, 0.f};
        if (gr < n) v = *(const float4*)&A[gr * FIN + c4 * 4];
        _Float16 h0 = (_Float16)v.x, h1 = (_Float16)v.y;
        _Float16 h2 = (_Float16)v.z, h3 = (_Float16)v.w;
        h4v hh = {h0, h1, h2, h3};
        h4v ll = {(_Float16)(v.x - (float)h0), (_Float16)(v.y - (float)h1),
                  (_Float16)(v.z - (float)h2), (_Float16)(v.w - (float)h3)};
        *(h4v*)&Ahs[r * LSTR + c4 * 4] = hh;
        *(h4v*)&Als[r * LSTR + c4 * 4] = ll;
    }

    const int wc = w % NWC;
    const int wr = w / NWC;
    const int colbase = wc * CT * 16;
    const int bk = (lane >> 4) * 8;
    h8v Bh[CT][KS], Bl[CT][KS];
    #pragma unroll
    for (int ct = 0; ct < CT; ++ct) {
        int c = colbase + ct * 16 + (lane & 15);
        #pragma unroll
        for (int kk = 0; kk < KS; ++kk) {
            Bh[ct][kk] = *(const h8v*)&Wh[(size_t)c * FIN + kk * 32 + bk];
            Bl[ct][kk] = *(const h8v*)&Wl[(size_t)c * FIN + kk * 32 + bk];
        }
    }

    __syncthreads();

    f32x4 acc[4][CT];
    #pragma unroll
    for (int rt = 0; rt < 4; ++rt)
        #pragma unroll
        for (int ct = 0; ct < CT; ++ct)
            acc[rt][ct] = (f32x4){0.f, 0.f, 0.f, 0.f};

    #pragma unroll
    for (int rt = 0; rt < 4; ++rt) {
        const int r = wr * 64 + rt * 16 + (lane & 15);
        #pragma unroll
        for (int kk = 0; kk < KS; ++kk) {
            h8v ah = *(const h8v*)&Ahs[r * LSTR + kk * 32 + bk];
            h8v al = *(const h8v*)&Als[r * LSTR + kk * 32 + bk];
            #pragma unroll
            for (int ct = 0; ct < CT; ++ct) {
                acc[rt][ct] = __builtin_amdgcn_mfma_f32_16x16x32_f16(ah, Bh[ct][kk], acc[rt][ct], 0, 0, 0);
                acc[rt][ct] = __builtin_amdgcn_mfma_f32_16x16x32_f16(ah, Bl[ct][kk], acc[rt][ct], 0, 0, 0);
                acc[rt][ct] = __builtin_amdgcn_mfma_f32_16x16x32_f16(al, Bh[ct][kk], acc[rt][ct], 0, 0, 0);
            }
        }
    }

    #pragma unroll
    for (int rt = 0; rt < 4; ++rt) {
        const long rbase = row0 + wr * 64 + rt * 16 + (lane >> 4) * 4;
        #pragma unroll
        for (int ct = 0; ct < CT; ++ct) {
            const int col = colbase + ct * 16 + (lane & 15);
            if (OMODE == 1) {
                const float bv = bias[col];
                #pragma unroll
                for (int j = 0; j < 4; ++j) {
                    long r = rbase + j;
                    if (r < n)
                        ((float*)Cv)[r * FOUT + col] = fmaxf(acc[rt][ct][j] + bv, 0.f);
                }
            } else {
                #pragma unroll
                for (int j = 0; j < 4; ++j) {
                    long r = rbase + j;
                    if (r < n)
                        ((__half*)Cv)[r * FOUT + col] = __float2half(acc[rt][ct][j]);
                }
            }
        }
    }
}

// ---------------- fp16-gather aggregation ----------------

__device__ __forceinline__ void hacc8(float acc[8], uint4 u, float w) {
    __half2 h; float2 f;
    h = *(__half2*)&u.x; f = __half22float2(h); acc[0] += w * f.x; acc[1] += w * f.y;
    h = *(__half2*)&u.y; f = __half22float2(h); acc[2] += w * f.x; acc[3] += w * f.y;
    h = *(__half2*)&u.z; f = __half22float2(h); acc[4] += w * f.x; acc[5] += w * f.y;
    h = *(__half2*)&u.w; f = __half22float2(h); acc[6] += w * f.x; acc[7] += w * f.y;
}

template<int F, bool BR>
__global__ __launch_bounds__(256) void aggh_kernel(const __half* __restrict__ tin,
        const float* __restrict__ bias, const float* __restrict__ dinv,
        const int* __restrict__ rp, const long long* __restrict__ cn,
        float* __restrict__ out, int n) {
    constexpr int LPR   = F / 8;
    constexpr int SLOTS = 64 / LPR;
    const int lane = threadIdx.x & 63;
    const int node = blockIdx.x * 4 + (threadIdx.x >> 6);
    if (node >= n) return;
    const int l    = lane % LPR;
    const int slot = lane / LPR;
    const uint4* base = (const uint4*)tin + l;
    const int e0 = rp[node], e1 = rp[node + 1];
    float acc[8] = {0.f, 0.f, 0.f, 0.f, 0.f, 0.f, 0.f, 0.f};
    if (slot == 0) {
        float di = dinv[node];
        uint4 u = base[(size_t)node * LPR];
        hacc8(acc, u, di * di);
    }
    int p = e0 + slot;
    for (; p + 3 * SLOTS < e1; p += 4 * SLOTS) {
        long long r0 = __builtin_nontemporal_load(cn + p);
        long long r1 = __builtin_nontemporal_load(cn + p + SLOTS);
        long long r2 = __builtin_nontemporal_load(cn + p + 2 * SLOTS);
        long long r3 = __builtin_nontemporal_load(cn + p + 3 * SLOTS);
        uint4 u0 = base[(size_t)(unsigned)r0 * LPR];
        uint4 u1 = base[(size_t)(unsigned)r1 * LPR];
        uint4 u2 = base[(size_t)(unsigned)r2 * LPR];
        uint4 u3 = base[(size_t)(unsigned)r3 * LPR];
        hacc8(acc, u0, __int_as_float((int)(r0 >> 32)));
        hacc8(acc, u1, __int_as_float((int)(r1 >> 32)));
        hacc8(acc, u2, __int_as_float((int)(r2 >> 32)));
        hacc8(acc, u3, __int_as_float((int)(r3 >> 32)));
    }
    for (; p + SLOTS < e1; p += 2 * SLOTS) {
        long long r0 = __builtin_nontemporal_load(cn + p);
        long long r1 = __builtin_nontemporal_load(cn + p + SLOTS);
        uint4 u0 = base[(size_t)(unsigned)r0 * LPR];
        uint4 u1 = base[(size_t)(unsigned)r1 * LPR];
        hacc8(acc, u0, __int_as_float((int)(r0 >> 32)));
        hacc8(acc, u1, __int_as_float((int)(r1 >> 32)));
    }
    if (p < e1) {
        long long r0 = __builtin_nontemporal_load(cn + p);
        uint4 u0 = base[(size_t)(unsigned)r0 * LPR];
        hacc8(acc, u0, __int_as_float((int)(r0 >> 32)));
    }
    #pragma unroll
    for (int off = 32; off >= LPR; off >>= 1) {
        #pragma unroll
        for (int j = 0; j < 8; ++j) acc[j] += __shfl_xor(acc[j], off);
    }
    if (slot == 0) {
        if (BR) {
            #pragma unroll
            for (int j = 0; j < 8; ++j)
                acc[j] = fmaxf(acc[j] + bias[l * 8 + j], 0.f);
        }
        f4 lo = {acc[0], acc[1], acc[2], acc[3]};
        f4 hi = {acc[4], acc[5], acc[6], acc[7]};
        float* o = out + (size_t)node * F + l * 8;
        __builtin_nontemporal_store(lo, (f4*)o);
        __builtin_nontemporal_store(hi, (f4*)(o + 4));
    }
}

// a2-aggregation (F=32) with fused a3 dot: wlin[node] = relu(agg+ba2) . A3
__global__ __launch_bounds__(256) void aggh32a_kernel(const __half* __restrict__ tin,
        const float* __restrict__ ba2, const float* __restrict__ A3,
        const float* __restrict__ dinv, const int* __restrict__ rp,
        const long long* __restrict__ cn, float* __restrict__ wlin, int n) {
    constexpr int LPR   = 4;
    constexpr int SLOTS = 16;
    const int lane = threadIdx.x & 63;
    const int node = blockIdx.x * 4 + (threadIdx.x >> 6);
    if (node >= n) return;
    const int l    = lane % LPR;
    const int slot = lane / LPR;
    const uint4* base = (const uint4*)tin + l;
    const int e0 = rp[node], e1 = rp[node + 1];
    float acc[8] = {0.f, 0.f, 0.f, 0.f, 0.f, 0.f, 0.f, 0.f};
    if (slot == 0) {
        float di = dinv[node];
        uint4 u = base[(size_t)node * LPR];
        hacc8(acc, u, di * di);
    }
    int p = e0 + slot;
    for (; p + SLOTS < e1; p += 2 * SLOTS) {
        long long r0 = __builtin_nontemporal_load(cn + p);
        long long r1 = __builtin_nontemporal_load(cn + p + SLOTS);
        uint4 u0 = base[(size_t)(unsigned)r0 * LPR];
        uint4 u1 = base[(size_t)(unsigned)r1 * LPR];
        hacc8(acc, u0, __int_as_float((int)(r0 >> 32)));
        hacc8(acc, u1, __int_as_float((int)(r1 >> 32)));
    }
    if (p < e1) {
        long long r0 = __builtin_nontemporal_load(cn + p);
        uint4 u0 = base[(size_t)(unsigned)r0 * LPR];
        hacc8(acc, u0, __int_as_float((int)(r0 >> 32)));
    }
    #pragma unroll
    for (int off = 32; off >= LPR; off >>= 1) {
        #pragma unroll
        for (int j = 0; j < 8; ++j) acc[j] += __shfl_xor(acc[j], off);
    }
    if (slot == 0) {
        float part = 0.f;
        #pragma unroll
        for (int j = 0; j < 8; ++j)
            part += fmaxf(acc[j] + ba2[l * 8 + j], 0.f) * A3[l * 8 + j];
        part += __shfl_xor(part, 1);
        part += __shfl_xor(part, 2);
        if (l == 0) wlin[node] = part;
    }
}

// F=1 aggregation for the attention scalar
__global__ void agg1_kernel(const float* __restrict__ tin, const float* __restrict__ bias,
        const float* __restrict__ dinv, const int* __restrict__ rp,
        const long long* __restrict__ cn, float* __restrict__ out, int n) {
    int i = blockIdx.x * 256 + threadIdx.x;
    if (i >= n) return;
    float di = dinv[i];
    float acc = di * di * tin[i];
    int e0 = rp[i], e1 = rp[i + 1];
    int p = e0;
    float a0 = 0.f, a1 = 0.f, a2 = 0.f, a3 = 0.f;
    for (; p + 3 < e1; p += 4) {
        long long r0 = __builtin_nontemporal_load(cn + p);
        long long r1 = __builtin_nontemporal_load(cn + p + 1);
        long long r2 = __builtin_nontemporal_load(cn + p + 2);
        long long r3 = __builtin_nontemporal_load(cn + p + 3);
        a0 += __int_as_float((int)(r0 >> 32)) * tin[(int)(unsigned)r0];
        a1 += __int_as_float((int)(r1 >> 32)) * tin[(int)(unsigned)r1];
        a2 += __int_as_float((int)(r2 >> 32)) * tin[(int)(unsigned)r2];
        a3 += __int_as_float((int)(r3 >> 32)) * tin[(int)(unsigned)r3];
    }
    for (; p < e1; ++p) {
        long long r0 = __builtin_nontemporal_load(cn + p);
        a0 += __int_as_float((int)(r0 >> 32)) * tin[(int)(unsigned)r0];
    }
    acc += a0 + a1 + a2 + a3 + bias[0];
    out[i] = acc > 0.f ? acc : 0.f;
}

// ---------------- fused per-graph softmax (max + exp + sum) ----------------

__global__ __launch_bounds__(256) void smexp_kernel(const float* __restrict__ w,
        const int* __restrict__ gstart, float* __restrict__ gsum,
        float* __restrict__ e) {
    const int g = blockIdx.x;
    const int a = gstart[g], b = gstart[g + 1];
    const int tid = threadIdx.x;
    __shared__ float red[4];
    float m = 0.f;                       // w >= 0 (post-relu)
    for (int i = a + tid; i < b; i += 256) m = fmaxf(m, w[i]);
    #pragma unroll
    for (int off = 32; off > 0; off >>= 1) m = fmaxf(m, __shfl_xor(m, off));
    if ((tid & 63) == 0) red[tid >> 6] = m;
    __syncthreads();
    m = fmaxf(fmaxf(red[0], red[1]), fmaxf(red[2], red[3]));
    float s = 0.f;
    for (int i = a + tid; i < b; i += 256) {
        float ex = expf(w[i] - m);
        e[i] = ex;
        s += ex;
    }
    #pragma unroll
    for (int off = 32; off > 0; off >>= 1) s += __shfl_xor(s, off);
    __syncthreads();
    if ((tid & 63) == 0) red[tid >> 6] = s;
    __syncthreads();
    if (tid == 0) gsum[g] = red[0] + red[1] + red[2] + red[3];
}

// ---------------- attention pooling ----------------

__global__ __launch_bounds__(128) void pool_kernel(const float* __restrict__ f3,
        const float* __restrict__ e, const float* __restrict__ gsum,
        const int* __restrict__ gstart, float* __restrict__ pooled) {
    constexpr int SPG = 64;
    const int g = blockIdx.x / SPG, s = blockIdx.x % SPG;
    const int a = gstart[g], bnd = gstart[g + 1];
    const int len = bnd - a;
    if (len <= 0) return;
    const int chunk = (len + SPG - 1) / SPG;
    const int lo = a + s * chunk;
    const int hi = min(lo + chunk, bnd);
    if (lo >= hi) return;
    const float inv = 1.f / (gsum[g] + 1e-16f);
    const int tid = threadIdx.x;
    const int lane4 = tid & 31;
    const int rs    = tid >> 5;
    f4 acc = {0.f, 0.f, 0.f, 0.f};
    for (int i = lo + rs; i < hi; i += 4) {
        float w = e[i] * inv;
        f4 v = *(const f4*)&f3[(size_t)i * FH + lane4 * 4];
        acc.x += w * v.x; acc.y += w * v.y;
        acc.z += w * v.z; acc.w += w * v.w;
    }
    acc.x += __shfl_xor(acc.x, 32);
    acc.y += __shfl_xor(acc.y, 32);
    acc.z += __shfl_xor(acc.z, 32);
    acc.w += __shfl_xor(acc.w, 32);
    __shared__ float sm[128];
    if (tid >= 64 && tid < 96) *(f4*)&sm[(tid - 64) * 4] = acc;
    __syncthreads();
    if (tid < 32) {
        f4 o = *(f4*)&sm[tid * 4];
        o.x += acc.x; o.y += acc.y; o.z += acc.z; o.w += acc.w;
        float* dst = &pooled[g * FH + tid * 4];
        atomicAdd(dst + 0, o.x);
        atomicAdd(dst + 1, o.y);
        atomicAdd(dst + 2, o.z);
        atomicAdd(dst + 3, o.w);
    }
}

// ---------------- MLP ----------------

__global__ __launch_bounds__(128) void mlp1_kernel(const float* __restrict__ pooled,
        const float* __restrict__ M1, const float* __restrict__ bm1,
        float* __restrict__ hidden) {
    __shared__ float pr[FH];
    int g = blockIdx.x, j = threadIdx.x;
    pr[j] = pooled[g * FH + j];
    __syncthreads();
    float acc = bm1[j];
    #pragma unroll 8
    for (int k = 0; k < FH; ++k) acc += pr[k] * M1[k * FH + j];
    hidden[g * FH + j] = acc > 0.f ? acc : 0.f;
}

__global__ __launch_bounds__(256) void mlp2_kernel(const float* __restrict__ hidden,
        const float* __restrict__ M2, const float* __restrict__ bm2,
        float* __restrict__ out) {
    __shared__ float hr[FH];
    int g = blockIdx.x, j = threadIdx.x;
    if (j < FH) hr[j] = hidden[g * FH + j];
    __syncthreads();
    float acc = bm2[j];
    #pragma unroll 8
    for (int k = 0; k < FH; ++k) acc += hr[k] * M2[k * DOUT + j];
    out[g * DOUT + j] = acc;
}

// ---------------------------------------------------------------------------

extern "C" void kernel_launch(void* const* d_in, const int* in_sizes, int n_in,
                              void* d_out, int out_size, void* d_ws, size_t ws_size,
                              hipStream_t stream) {
    const float* x   = (const float*)d_in[0];
    const int*   ei  = (const int*)d_in[1];
    const int*   batch = (const int*)d_in[2];
    const float* W1  = (const float*)d_in[3];
    const float* b1  = (const float*)d_in[4];
    const float* W2  = (const float*)d_in[5];
    const float* b2  = (const float*)d_in[6];
    const float* W3  = (const float*)d_in[7];
    const float* b3  = (const float*)d_in[8];
    const float* A1  = (const float*)d_in[9];
    const float* ba1 = (const float*)d_in[10];
    const float* A2  = (const float*)d_in[11];
    const float* ba2 = (const float*)d_in[12];
    const float* A3  = (const float*)d_in[13];
    const float* ba3 = (const float*)d_in[14];
    const float* M1  = (const float*)d_in[15];
    const float* bm1 = (const float*)d_in[16];
    const float* M2  = (const float*)d_in[17];
    const float* bm2 = (const float*)d_in[18];

    const int N = in_sizes[0] / DIN;
    const int E = in_sizes[1] / 2;
    const int G = out_size / DOUT;
    const int* src = ei;
    const int* dst = ei + E;
    float* out = (float*)d_out;

    // bucket shift: smallest s with ceil(N / 2^s) <= NBUK (=9 for N=50000)
    int shift = 9;
    while (((N + (1 << shift) - 1) >> shift) > NBUK) ++shift;
    const int nbuckets = (N + (1 << shift) - 1) >> shift;

    // workspace carve (aliased; see lifetime notes)
    char* p = (char*)d_ws;
    auto alloc = [&](size_t bytes) -> void* {
        void* r = (void*)p;
        p += (bytes + 255) & ~(size_t)255;
        return r;
    };
    float* dinv  = (float*)alloc((size_t)N * 4);
    int*   cnt   = (int*)alloc((size_t)N * 4);
    int*   rp    = (int*)alloc((size_t)(N + 1) * 4);
    long long* cn = (long long*)alloc((size_t)E * 8);
    float* SY    = (float*)alloc((size_t)N * FH * 4);   // Y, then f3
    float* SA    = (float*)alloc((size_t)N * FH * 4);   // entries, then f2
    __half* ST   = (__half*)alloc((size_t)N * FH * 2);  // t2, then t3 (fp16)
    char*  SX    = (char*)alloc((size_t)N * 256);       // xh (fp16)
    __half* u2   = (__half*)alloc((size_t)N * 32 * 2);
    float* wlin  = (float*)alloc((size_t)N * 4);
    float* wact  = (float*)alloc((size_t)N * 4);
    float* ebuf  = (float*)alloc((size_t)N * 4);
    float* gsum  = (float*)alloc((size_t)G * 4);
    int*   gstart= (int*)alloc((size_t)(G + 1) * 4);
    float* pooled= (float*)alloc((size_t)G * FH * 4);
    float* hidden= (float*)alloc((size_t)G * FH * 4);
    int*   bsum  = (int*)alloc(256 * 4);
    int*   boff  = (int*)alloc(256 * 4);
    int*   bcur  = (int*)alloc(NBUK * 4);
    _Float16* WT = (_Float16*)alloc((size_t)118784 * 2); // split-fp16 weights

    __half* xh = (__half*)SX;   // [N,128] fp16 (dead after Y-agg)
    unsigned long long* entries = (unsigned long long*)SA;  // NBUK*ECAP*8 = 16.8MB <= N*FH*4

    hipMemsetAsync(pooled, 0, (size_t)G * FH * 4, stream);

    const int nb = (N + 255) / 256;
    const int NB = (N + 511) / 512;

    wprep_kernel<<<232, 256, 0, stream>>>(W1, W2, W3, A1, A2, WT, bcur);
    // block-local sort + coalesced frontier appends (no global atomics on cnt)
    ebucket_kernel<<<(E + 2047) / 2048, 256, 0, stream>>>(src, dst, bcur, entries, E, shift);
    // degree histogram from bucketed entries (coalesced cnt writes)
    ecount_kernel<<<nbuckets, 512, 0, stream>>>(entries, bcur, cnt, N, shift);
    scan1_kernel<<<NB, 256, 0, stream>>>(cnt, bsum, dinv, N);
    scan2_kernel<<<1, 64, 0, stream>>>(bsum, boff, rp + N, NB);
    scan3_kernel<<<NB, 256, 0, stream>>>(cnt, boff, rp, N);
    gstart_kernel<<<1, 128, 0, stream>>>(batch, gstart, N, G);
    ecsr_kernel<<<nbuckets, 512, 0, stream>>>(entries, rp, dinv, cn, N, shift);

    const long n8 = (long)N * FH / 8;
    cvt16_kernel<<<(int)((n8 + 255) / 256), 256, 0, stream>>>(x, xh, n8);

    const int gb64 = (N + 63) / 64;
    const int agb  = (N + 3) / 4;

    // shared layer-1 aggregation: Y = A_hat x
    aggh_kernel<FH, false><<<agb, 256, 0, stream>>>(xh, nullptr, dinv, rp, cn, SY, N);

    // fused layer-1+2 linears: Y -> t2 (ST), u2
    fusedl1_kernel<<<gb64, 256, 0, stream>>>(SY, WT, b1, ba1, (__half*)ST, u2, N);

    // feature branch
    aggh_kernel<FH, true><<<agb, 256, 0, stream>>>(ST, b2, dinv, rp, cn, SA, N);          // f2
    mgemm_kernel<FH, FH, 2><<<gb64, 256, 0, stream>>>(SA, WT + 65536, WT + 81920, nullptr, ST, N); // t3
    aggh_kernel<FH, true><<<agb, 256, 0, stream>>>(ST, b3, dinv, rp, cn, SY, N);          // f3 -> SY

    // attention branch: a2-agg with fused a3 dot -> wlin, then scalar agg
    aggh32a_kernel<<<agb, 256, 0, stream>>>(u2, ba2, A3, dinv, rp, cn, wlin, N);
    agg1_kernel<<<nb, 256, 0, stream>>>(wlin, ba3, dinv, rp, cn, wact, N);

    // fused per-graph softmax + attention pooling
    smexp_kernel<<<G, 256, 0, stream>>>(wact, gstart, gsum, ebuf);
    pool_kernel<<<G * 64, 128, 0, stream>>>(SY, ebuf, gsum, gstart, pooled);

    // MLP
    mlp1_kernel<<<G, 128, 0, stream>>>(pooled, M1, bm1, hidden);
    mlp2_kernel<<<G, 256, 0, stream>>>(hidden, M2, bm2, out);
}